// Round 4
// baseline (940.910 us; speedup 1.0000x reference)
//
#include <hip/hip_runtime.h>
#include <hip/hip_bf16.h>

#define N_NODES 20000
#define N_EDGES 160000
#define DIN_NODE 256
#define DIN_EDGE 64
#define DF 128      // feature dim
#define HH 256      // edge-MLP hidden dim
#define TT 17       // node types
#define NE_PAD_SLOTS 20544   // 642 blocks * 32 (type-padded bucket list)

typedef __attribute__((ext_vector_type(8))) short short8v;   // 8 bf16
typedef __attribute__((ext_vector_type(4))) float f32x4;     // MFMA C/D frag

// fp32 -> bf16 round-to-nearest-even
__device__ __forceinline__ unsigned short f2bf(float f) {
  unsigned int u = __builtin_bit_cast(unsigned int, f);
  u += 0x7FFFu + ((u >> 16) & 1u);
  return (unsigned short)(u >> 16);
}

__device__ __forceinline__ short8v pack8(float4 a, float4 b) {
  short8v o;
  o[0] = (short)f2bf(a.x); o[1] = (short)f2bf(a.y);
  o[2] = (short)f2bf(a.z); o[3] = (short)f2bf(a.w);
  o[4] = (short)f2bf(b.x); o[5] = (short)f2bf(b.y);
  o[6] = (short)f2bf(b.z); o[7] = (short)f2bf(b.w);
  return o;
}

// ---------------------------------------------------------------------------
// Pack fp32 weight [batch][K][N] into MFMA B-fragment order:
// tile = b*(K/32)*(N/16) + kt*(N/16) + nt; elem j of lane l =
// W[b][kt*32 + 8*(l>>4) + j][nt*16 + (l&15)].
// ---------------------------------------------------------------------------
__global__ __launch_bounds__(256) void k_pack_w(
    const float* __restrict__ w, unsigned short* __restrict__ out,
    int Kdim, int Ndim, int batch) {
  const int tile = blockIdx.x * 4 + (threadIdx.x >> 6);
  const int l = threadIdx.x & 63;
  const int ntTiles = Ndim >> 4;
  const int tilesPer = (Kdim >> 5) * ntTiles;
  if (tile >= tilesPer * batch) return;
  const int bt = tile / tilesPer;
  const int rr = tile - bt * tilesPer;
  const int kt = rr / ntTiles, nt = rr % ntTiles;
  const float* wb = w + (size_t)bt * Kdim * Ndim;
  const int col = (nt << 4) + (l & 15);
  const int k0 = (kt << 5) + ((l >> 4) << 3);
  unsigned short* o = out + (((size_t)tile << 6) + l) * 8;
#pragma unroll
  for (int j = 0; j < 8; ++j) o[j] = f2bf(wb[(size_t)(k0 + j) * Ndim + col]);
}

// ---------------------------------------------------------------------------
// Node-type bucketing (padded segments, 32-aligned per type).
// ---------------------------------------------------------------------------
__global__ void k_count(const int* __restrict__ types, int* __restrict__ cnt) {
  const int n = blockIdx.x * 256 + threadIdx.x;
  if (n < N_NODES) atomicAdd(&cnt[types[n]], 1);
}
__global__ void k_prefix(const int* __restrict__ cnt, int* __restrict__ poff,
                         int* __restrict__ woff) {
  if (threadIdx.x == 0) {
    int cur = 0;
    for (int t = 0; t < TT; ++t) {
      poff[t] = cur; woff[t] = cur;
      cur += (cnt[t] + 31) & ~31;
    }
  }
}
__global__ void k_scatter(const int* __restrict__ types, int* __restrict__ woff,
                          int* __restrict__ bucket) {
  const int n = blockIdx.x * 256 + threadIdx.x;
  if (n < N_NODES) {
    const int pos = atomicAdd(&woff[types[n]], 1);
    bucket[pos] = n;
  }
}

// ---------------------------------------------------------------------------
// Type-batched node embedding: 32 nodes of ONE type per block.
// ---------------------------------------------------------------------------
__global__ __launch_bounds__(256) void k_node_embed_mfma(
    const float* __restrict__ x, const int* __restrict__ bucket,
    const int* __restrict__ types,
    const unsigned short* __restrict__ wp1, const float* __restrict__ b1,
    const unsigned short* __restrict__ wp2, const float* __restrict__ b2,
    unsigned short* __restrict__ nf0b) {
  __shared__ __align__(16) unsigned char A[32 * 512];   // 32 x 256 bf16
  __shared__ __align__(16) unsigned char Hb[32 * 256];  // 32 x 128 bf16
  __shared__ int sn[32];
  const int t = threadIdx.x;
  const int r0 = blockIdx.x * 32;
  if (t < 32) sn[t] = bucket[r0 + t];
  __syncthreads();
  if (sn[0] < 0) return;          // whole window is padding
  const int ty = types[sn[0]];

#pragma unroll
  for (int j = 0; j < 4; ++j) {
    const int q = j * 256 + t;
    const int i = q >> 5, c = q & 31;
    const int nd = sn[i];
    short8v o;
    if (nd >= 0) {
      const float* xr = x + (size_t)nd * DIN_NODE + c * 8;
      o = pack8(*reinterpret_cast<const float4*>(xr),
                *reinterpret_cast<const float4*>(xr + 4));
    } else {
#pragma unroll
      for (int k = 0; k < 8; ++k) o[k] = 0;
    }
    *reinterpret_cast<short8v*>(A + ((i * 512 + c * 16) ^ ((i & 7) << 4))) = o;
  }
  __syncthreads();

  const int w = t >> 6, l = t & 63, lr = l & 15, lg = l >> 4;
  const int sw = (lr & 7) << 4;
  const int row0 = lr, row1 = 16 + lr;

  f32x4 acc[2][2];
#pragma unroll
  for (int mt = 0; mt < 2; ++mt)
#pragma unroll
    for (int q = 0; q < 2; ++q)
#pragma unroll
      for (int r = 0; r < 4; ++r) acc[mt][q][r] = 0.f;

#pragma unroll
  for (int kt = 0; kt < 8; ++kt) {
    const short8v a0 = *reinterpret_cast<const short8v*>(
        A + ((row0 * 512 + kt * 64 + lg * 16) ^ sw));
    const short8v a1 = *reinterpret_cast<const short8v*>(
        A + ((row1 * 512 + kt * 64 + lg * 16) ^ sw));
#pragma unroll
    for (int q = 0; q < 2; ++q) {
      const short8v bq = *reinterpret_cast<const short8v*>(
          wp1 + (((size_t)(ty * 64 + kt * 8 + 2 * w + q) * 64 + l) << 3));
      acc[0][q] = __builtin_amdgcn_mfma_f32_16x16x32_bf16(a0, bq, acc[0][q], 0, 0, 0);
      acc[1][q] = __builtin_amdgcn_mfma_f32_16x16x32_bf16(a1, bq, acc[1][q], 0, 0, 0);
    }
  }
#pragma unroll
  for (int q = 0; q < 2; ++q) {
    const int col = (2 * w + q) * 16 + lr;
    const float bias = b1[ty * DF + col];
#pragma unroll
    for (int mt = 0; mt < 2; ++mt)
#pragma unroll
      for (int r = 0; r < 4; ++r) {
        const int row = mt * 16 + lg * 4 + r;
        *reinterpret_cast<unsigned short*>(
            Hb + ((row * 256 + col * 2) ^ ((row & 7) << 4))) =
            f2bf(fmaxf(acc[mt][q][r] + bias, 0.f));
      }
  }
  __syncthreads();

  f32x4 acc2[2][2];
#pragma unroll
  for (int mt = 0; mt < 2; ++mt)
#pragma unroll
    for (int q = 0; q < 2; ++q)
#pragma unroll
      for (int r = 0; r < 4; ++r) acc2[mt][q][r] = 0.f;
#pragma unroll
  for (int kt = 0; kt < 4; ++kt) {
    const short8v a0 = *reinterpret_cast<const short8v*>(
        Hb + ((row0 * 256 + kt * 64 + lg * 16) ^ sw));
    const short8v a1 = *reinterpret_cast<const short8v*>(
        Hb + ((row1 * 256 + kt * 64 + lg * 16) ^ sw));
#pragma unroll
    for (int q = 0; q < 2; ++q) {
      const short8v bq = *reinterpret_cast<const short8v*>(
          wp2 + (((size_t)(ty * 32 + kt * 8 + 2 * w + q) * 64 + l) << 3));
      acc2[0][q] = __builtin_amdgcn_mfma_f32_16x16x32_bf16(a0, bq, acc2[0][q], 0, 0, 0);
      acc2[1][q] = __builtin_amdgcn_mfma_f32_16x16x32_bf16(a1, bq, acc2[1][q], 0, 0, 0);
    }
  }
#pragma unroll
  for (int q = 0; q < 2; ++q) {
    const int col = (2 * w + q) * 16 + lr;
    const float bias = b2[ty * DF + col];
#pragma unroll
    for (int mt = 0; mt < 2; ++mt)
#pragma unroll
      for (int r = 0; r < 4; ++r) {
        const int row = mt * 16 + lg * 4 + r;
        const int nd = sn[row];
        if (nd >= 0)
          nf0b[(size_t)nd * DF + col] = f2bf(acc2[mt][q][r] + bias);
      }
  }
}

// ---------------------------------------------------------------------------
// Edge embedding MFMA: 64 -> 128 relu -> 128, 32 edges/block, bf16 out.
// ---------------------------------------------------------------------------
__global__ __launch_bounds__(256) void k_edge_embed_mfma(
    const float* __restrict__ ea,
    const unsigned short* __restrict__ wp1, const float* __restrict__ b1,
    const unsigned short* __restrict__ wp2, const float* __restrict__ b2,
    unsigned short* __restrict__ ef0b) {
  __shared__ __align__(16) unsigned char A[32 * 128];   // 32 x 64 bf16
  __shared__ __align__(16) unsigned char Hb[32 * 256];  // 32 x 128 bf16
  const int t = threadIdx.x;
  const int e0 = blockIdx.x * 32;
  {
    const int i = t >> 3, c = t & 7;
    const float* xr = ea + (size_t)(e0 + i) * DIN_EDGE + c * 8;
    const short8v o = pack8(*reinterpret_cast<const float4*>(xr),
                            *reinterpret_cast<const float4*>(xr + 4));
    *reinterpret_cast<short8v*>(A + ((i * 128 + c * 16) ^ ((i & 7) << 4))) = o;
  }
  __syncthreads();

  const int w = t >> 6, l = t & 63, lr = l & 15, lg = l >> 4;
  const int sw = (lr & 7) << 4;
  const int row0 = lr, row1 = 16 + lr;

  f32x4 acc[2][2];
#pragma unroll
  for (int mt = 0; mt < 2; ++mt)
#pragma unroll
    for (int q = 0; q < 2; ++q)
#pragma unroll
      for (int r = 0; r < 4; ++r) acc[mt][q][r] = 0.f;
#pragma unroll
  for (int kt = 0; kt < 2; ++kt) {
    const short8v a0 = *reinterpret_cast<const short8v*>(
        A + ((row0 * 128 + kt * 64 + lg * 16) ^ sw));
    const short8v a1 = *reinterpret_cast<const short8v*>(
        A + ((row1 * 128 + kt * 64 + lg * 16) ^ sw));
#pragma unroll
    for (int q = 0; q < 2; ++q) {
      const short8v bq = *reinterpret_cast<const short8v*>(
          wp1 + (((size_t)(kt * 8 + 2 * w + q) * 64 + l) << 3));
      acc[0][q] = __builtin_amdgcn_mfma_f32_16x16x32_bf16(a0, bq, acc[0][q], 0, 0, 0);
      acc[1][q] = __builtin_amdgcn_mfma_f32_16x16x32_bf16(a1, bq, acc[1][q], 0, 0, 0);
    }
  }
#pragma unroll
  for (int q = 0; q < 2; ++q) {
    const int col = (2 * w + q) * 16 + lr;
    const float bias = b1[col];
#pragma unroll
    for (int mt = 0; mt < 2; ++mt)
#pragma unroll
      for (int r = 0; r < 4; ++r) {
        const int row = mt * 16 + lg * 4 + r;
        *reinterpret_cast<unsigned short*>(
            Hb + ((row * 256 + col * 2) ^ ((row & 7) << 4))) =
            f2bf(fmaxf(acc[mt][q][r] + bias, 0.f));
      }
  }
  __syncthreads();

  f32x4 acc2[2][2];
#pragma unroll
  for (int mt = 0; mt < 2; ++mt)
#pragma unroll
    for (int q = 0; q < 2; ++q)
#pragma unroll
      for (int r = 0; r < 4; ++r) acc2[mt][q][r] = 0.f;
#pragma unroll
  for (int kt = 0; kt < 4; ++kt) {
    const short8v a0 = *reinterpret_cast<const short8v*>(
        Hb + ((row0 * 256 + kt * 64 + lg * 16) ^ sw));
    const short8v a1 = *reinterpret_cast<const short8v*>(
        Hb + ((row1 * 256 + kt * 64 + lg * 16) ^ sw));
#pragma unroll
    for (int q = 0; q < 2; ++q) {
      const short8v bq = *reinterpret_cast<const short8v*>(
          wp2 + (((size_t)(kt * 8 + 2 * w + q) * 64 + l) << 3));
      acc2[0][q] = __builtin_amdgcn_mfma_f32_16x16x32_bf16(a0, bq, acc2[0][q], 0, 0, 0);
      acc2[1][q] = __builtin_amdgcn_mfma_f32_16x16x32_bf16(a1, bq, acc2[1][q], 0, 0, 0);
    }
  }
#pragma unroll
  for (int q = 0; q < 2; ++q) {
    const int col = (2 * w + q) * 16 + lr;
    const float bias = b2[col];
#pragma unroll
    for (int mt = 0; mt < 2; ++mt)
#pragma unroll
      for (int r = 0; r < 4; ++r) {
        const int row = mt * 16 + lg * 4 + r;
        ef0b[(size_t)(e0 + row) * DF + col] = f2bf(acc2[mt][q][r] + bias);
      }
  }
}

// ---------------------------------------------------------------------------
// Edge MLP via MFMA v3: M=128 edges/block, 512 threads (8 waves, 2M x 4N).
// K-chunked (6 parts of 128), double-buffered LDS A, async reg-staged gather.
// Weight traffic amortized over 4x more edges than v2.
// ---------------------------------------------------------------------------
template <bool OUTF>
__global__ __launch_bounds__(512, 2) void k_edge_mlp_mfma(
    const unsigned short* __restrict__ nf0, const unsigned short* __restrict__ nf,
    const unsigned short* __restrict__ ef0, const unsigned short* __restrict__ ef_in,
    void* __restrict__ ef_out, float* __restrict__ agg,
    const int* __restrict__ srcv, const int* __restrict__ dstv,
    const unsigned short* __restrict__ wp1, const float* __restrict__ b1,
    const unsigned short* __restrict__ wp2, const float* __restrict__ b2) {
  __shared__ __align__(16) unsigned char Abuf[2][128 * 256];  // 2 x 32 KB
  __shared__ __align__(16) unsigned char Hbuf[128 * 512];     // 64 KB hidden
  __shared__ int sd0[128], sd1[128];
  const int t = threadIdx.x;
  const int e0 = blockIdx.x * 128;
  if (t < 128) sd0[t] = srcv[e0 + t];
  else if (t < 256) sd1[t - 128] = dstv[e0 + t - 128];
  __syncthreads();

  const int w = t >> 6, l = t & 63, lr = l & 15, lg = l >> 4;
  const int wm = w >> 2, wn = w & 3;
  const int sw = (lr & 7) << 4;

  short8v st[4];   // in-flight staging regs (T14 async split)

  auto load_part = [&](int p) {
#pragma unroll
    for (int j = 0; j < 4; ++j) {
      const int chunk = j * 512 + t;           // 2048 chunks of 16B
      const int i = chunk >> 4, c = chunk & 15;
      const unsigned short* bp;
      switch (p) {
        case 0: bp = nf0 + (size_t)sd1[i] * DF; break;
        case 1: bp = nf + (size_t)sd1[i] * DF; break;
        case 2: bp = nf0 + (size_t)sd0[i] * DF; break;
        case 3: bp = nf + (size_t)sd0[i] * DF; break;
        case 4: bp = ef0 + (size_t)(e0 + i) * DF; break;
        default: bp = ef_in + (size_t)(e0 + i) * DF; break;
      }
      st[j] = *reinterpret_cast<const short8v*>(bp + c * 8);
    }
  };
  auto write_part = [&](int buf) {
#pragma unroll
    for (int j = 0; j < 4; ++j) {
      const int chunk = j * 512 + t;
      const int i = chunk >> 4, c = chunk & 15;
      *reinterpret_cast<short8v*>(
          &Abuf[buf][(i * 256 + c * 16) ^ ((i & 7) << 4)]) = st[j];
    }
  };

  load_part(0);
  write_part(0);
  __syncthreads();

  // ---- layer 1: [128x768] @ [768x256], wave tile 64 edges x 64 cols --------
  f32x4 acc[4][4];
#pragma unroll
  for (int mt = 0; mt < 4; ++mt)
#pragma unroll
    for (int q = 0; q < 4; ++q)
#pragma unroll
      for (int r = 0; r < 4; ++r) acc[mt][q][r] = 0.f;

  for (int p = 0; p < 6; ++p) {
    if (p < 5) load_part(p + 1);     // issue gathers early; MFMAs hide latency
    const unsigned char* Ab = Abuf[p & 1];
#pragma unroll
    for (int kt = 0; kt < 4; ++kt) {
      short8v a[4];
#pragma unroll
      for (int mt = 0; mt < 4; ++mt)
        a[mt] = *reinterpret_cast<const short8v*>(
            Ab + (((wm * 64 + mt * 16 + lr) * 256 + kt * 64 + lg * 16) ^ sw));
      const int ktg = p * 4 + kt;
#pragma unroll
      for (int q = 0; q < 4; ++q) {
        const short8v bq = *reinterpret_cast<const short8v*>(
            wp1 + (((size_t)(ktg * 16 + wn * 4 + q) * 64 + l) << 3));
#pragma unroll
        for (int mt = 0; mt < 4; ++mt)
          acc[mt][q] =
              __builtin_amdgcn_mfma_f32_16x16x32_bf16(a[mt], bq, acc[mt][q], 0, 0, 0);
      }
    }
    if (p < 5) write_part((p + 1) & 1);   // other buffer than compute read
    __syncthreads();
  }

  // ---- hidden: bias + relu -> bf16 [128][256] swizzled ----------------------
#pragma unroll
  for (int q = 0; q < 4; ++q) {
    const int col = wn * 64 + q * 16 + lr;
    const float bias = b1[col];
#pragma unroll
    for (int mt = 0; mt < 4; ++mt)
#pragma unroll
      for (int r = 0; r < 4; ++r) {
        const int row = wm * 64 + mt * 16 + lg * 4 + r;
        *reinterpret_cast<unsigned short*>(
            Hbuf + ((row * 512 + col * 2) ^ ((row & 7) << 4))) =
            f2bf(fmaxf(acc[mt][q][r] + bias, 0.f));
      }
  }
  __syncthreads();

  // ---- layer 2: [128x256] @ [256x128], wave tile 64 edges x 32 cols --------
  f32x4 acc2[4][2];
#pragma unroll
  for (int mt = 0; mt < 4; ++mt)
#pragma unroll
    for (int q = 0; q < 2; ++q)
#pragma unroll
      for (int r = 0; r < 4; ++r) acc2[mt][q][r] = 0.f;
#pragma unroll
  for (int kt = 0; kt < 8; ++kt) {
    short8v a[4];
#pragma unroll
    for (int mt = 0; mt < 4; ++mt)
      a[mt] = *reinterpret_cast<const short8v*>(
          Hbuf + (((wm * 64 + mt * 16 + lr) * 512 + kt * 64 + lg * 16) ^ sw));
#pragma unroll
    for (int q = 0; q < 2; ++q) {
      const short8v bq = *reinterpret_cast<const short8v*>(
          wp2 + (((size_t)(kt * 8 + wn * 2 + q) * 64 + l) << 3));
#pragma unroll
      for (int mt = 0; mt < 4; ++mt)
        acc2[mt][q] =
            __builtin_amdgcn_mfma_f32_16x16x32_bf16(a[mt], bq, acc2[mt][q], 0, 0, 0);
    }
  }

  // ---- epilogue: bias, store ef, atomic agg[dst] ----------------------------
#pragma unroll
  for (int q = 0; q < 2; ++q) {
    const int n = wn * 32 + q * 16 + lr;
    const float bias = b2[n];
#pragma unroll
    for (int mt = 0; mt < 4; ++mt)
#pragma unroll
      for (int r = 0; r < 4; ++r) {
        const int m = wm * 64 + mt * 16 + lg * 4 + r;
        const float v = acc2[mt][q][r] + bias;
        if (OUTF)
          ((float*)ef_out)[(size_t)(e0 + m) * DF + n] = v;
        else
          ((unsigned short*)ef_out)[(size_t)(e0 + m) * DF + n] = f2bf(v);
        atomicAdd(&agg[(size_t)sd1[m] * DF + n], v);
      }
  }
}

// ---------------------------------------------------------------------------
// Node update MFMA: [nf0|nf|agg] (384) @ w + b, 32 nodes/block.
// ---------------------------------------------------------------------------
template <bool OUTF>
__global__ __launch_bounds__(256) void k_node_update_mfma(
    const unsigned short* __restrict__ nf0, const unsigned short* __restrict__ nfb,
    const float* __restrict__ agg, void* __restrict__ outp,
    const unsigned short* __restrict__ wp, const float* __restrict__ b) {
  __shared__ __align__(16) unsigned char A[32 * 768];   // 32 x 384 bf16
  const int t = threadIdx.x;
  const int n0 = blockIdx.x * 32;
#pragma unroll
  for (int j = 0; j < 6; ++j) {
    const int q = j * 256 + t;
    const int i = q / 48;
    const int cc = q - i * 48;
    const int p = cc >> 4, c = cc & 15;
    const int row = n0 + i;
    short8v o;
    if (p == 0)
      o = *reinterpret_cast<const short8v*>(nf0 + (size_t)row * DF + c * 8);
    else if (p == 1)
      o = *reinterpret_cast<const short8v*>(nfb + (size_t)row * DF + c * 8);
    else {
      const float* ar = agg + (size_t)row * DF + c * 8;
      o = pack8(*reinterpret_cast<const float4*>(ar),
                *reinterpret_cast<const float4*>(ar + 4));
    }
    *reinterpret_cast<short8v*>(
        A + ((i * 768 + p * 256 + c * 16) ^ ((i & 7) << 4))) = o;
  }
  __syncthreads();

  const int w = t >> 6, l = t & 63, lr = l & 15, lg = l >> 4;
  const int sw = (lr & 7) << 4;
  const int row0 = lr, row1 = 16 + lr;

  f32x4 acc[2][2];
#pragma unroll
  for (int mt = 0; mt < 2; ++mt)
#pragma unroll
    for (int q = 0; q < 2; ++q)
#pragma unroll
      for (int r = 0; r < 4; ++r) acc[mt][q][r] = 0.f;
#pragma unroll
  for (int kt = 0; kt < 12; ++kt) {
    const short8v a0 = *reinterpret_cast<const short8v*>(
        A + ((row0 * 768 + kt * 64 + lg * 16) ^ sw));
    const short8v a1 = *reinterpret_cast<const short8v*>(
        A + ((row1 * 768 + kt * 64 + lg * 16) ^ sw));
#pragma unroll
    for (int q = 0; q < 2; ++q) {
      const short8v bq = *reinterpret_cast<const short8v*>(
          wp + (((size_t)(kt * 8 + 2 * w + q) * 64 + l) << 3));
      acc[0][q] = __builtin_amdgcn_mfma_f32_16x16x32_bf16(a0, bq, acc[0][q], 0, 0, 0);
      acc[1][q] = __builtin_amdgcn_mfma_f32_16x16x32_bf16(a1, bq, acc[1][q], 0, 0, 0);
    }
  }
#pragma unroll
  for (int q = 0; q < 2; ++q) {
    const int col = (2 * w + q) * 16 + lr;
    const float bias = b[col];
#pragma unroll
    for (int mt = 0; mt < 2; ++mt)
#pragma unroll
      for (int r = 0; r < 4; ++r) {
        const int row = mt * 16 + lg * 4 + r;
        const float v = acc[mt][q][r] + bias;
        if (OUTF)
          ((float*)outp)[(size_t)(n0 + row) * DF + col] = v;
        else
          ((unsigned short*)outp)[(size_t)(n0 + row) * DF + col] = f2bf(v);
      }
  }
}

// ---------------------------------------------------------------------------
// Scalar classifier: relu(f @ w1 + b1) . w2 + b2, 32 rows/block.
// ---------------------------------------------------------------------------
template <bool INBF>
__global__ __launch_bounds__(256) void k_cls_scalar_mfma(
    const void* __restrict__ feat, const unsigned short* __restrict__ wp,
    const float* __restrict__ b1, const float* __restrict__ w2,
    const float* __restrict__ b2, float* __restrict__ out) {
  __shared__ __align__(16) unsigned char A[32 * 256];  // 32 x 128 bf16
  __shared__ float hid[32][136];
  __shared__ float w2s[DF];
  __shared__ float part[32][8];
  const int t = threadIdx.x;
  const int r0 = blockIdx.x * 32;
  if (t < DF) w2s[t] = w2[t];
#pragma unroll
  for (int j = 0; j < 2; ++j) {
    const int q = j * 256 + t;
    const int i = q >> 4, c = q & 15;
    short8v o;
    if (INBF) {
      o = *reinterpret_cast<const short8v*>(
          (const unsigned short*)feat + (size_t)(r0 + i) * DF + c * 8);
    } else {
      const float* fr = (const float*)feat + (size_t)(r0 + i) * DF + c * 8;
      o = pack8(*reinterpret_cast<const float4*>(fr),
                *reinterpret_cast<const float4*>(fr + 4));
    }
    *reinterpret_cast<short8v*>(A + ((i * 256 + c * 16) ^ ((i & 7) << 4))) = o;
  }
  __syncthreads();

  const int w = t >> 6, l = t & 63, lr = l & 15, lg = l >> 4;
  const int sw = (lr & 7) << 4;
  const int row0 = lr, row1 = 16 + lr;
  f32x4 acc[2][2];
#pragma unroll
  for (int mt = 0; mt < 2; ++mt)
#pragma unroll
    for (int q = 0; q < 2; ++q)
#pragma unroll
      for (int r = 0; r < 4; ++r) acc[mt][q][r] = 0.f;
#pragma unroll
  for (int kt = 0; kt < 4; ++kt) {
    const short8v a0 = *reinterpret_cast<const short8v*>(
        A + ((row0 * 256 + kt * 64 + lg * 16) ^ sw));
    const short8v a1 = *reinterpret_cast<const short8v*>(
        A + ((row1 * 256 + kt * 64 + lg * 16) ^ sw));
#pragma unroll
    for (int q = 0; q < 2; ++q) {
      const short8v bq = *reinterpret_cast<const short8v*>(
          wp + (((size_t)(kt * 8 + 2 * w + q) * 64 + l) << 3));
      acc[0][q] = __builtin_amdgcn_mfma_f32_16x16x32_bf16(a0, bq, acc[0][q], 0, 0, 0);
      acc[1][q] = __builtin_amdgcn_mfma_f32_16x16x32_bf16(a1, bq, acc[1][q], 0, 0, 0);
    }
  }
#pragma unroll
  for (int q = 0; q < 2; ++q) {
    const int col = (2 * w + q) * 16 + lr;
    const float bias = b1[col];
#pragma unroll
    for (int mt = 0; mt < 2; ++mt)
#pragma unroll
      for (int r = 0; r < 4; ++r) {
        const int row = mt * 16 + lg * 4 + r;
        hid[row][col] = fmaxf(acc[mt][q][r] + bias, 0.f);
      }
  }
  __syncthreads();
  {
    const int r = t >> 3, kc = t & 7;
    float s = 0.f;
#pragma unroll
    for (int u = 0; u < 16; ++u) s = fmaf(hid[r][kc * 16 + u], w2s[kc * 16 + u], s);
    part[r][kc] = s;
  }
  __syncthreads();
  if (t < 32) {
    float s = b2[0];
#pragma unroll
    for (int k = 0; k < 8; ++k) s += part[t][k];
    out[r0 + t] = s;
  }
}

// ---------------------------------------------------------------------------
// Class classifier: relu(f @ w1 + b1) @ w2[128,17] + b2, fp32 input.
// ---------------------------------------------------------------------------
__global__ __launch_bounds__(256) void k_cls_class_mfma(
    const float* __restrict__ feat, const unsigned short* __restrict__ wp,
    const float* __restrict__ b1, const float* __restrict__ w2,
    const float* __restrict__ b2, float* __restrict__ out) {
  __shared__ __align__(16) unsigned char A[32 * 256];
  __shared__ float hid[32][136];
  __shared__ float w2s[DF * TT];
  const int t = threadIdx.x;
  const int r0 = blockIdx.x * 32;
  for (int j = t; j < DF * TT; j += 256) w2s[j] = w2[j];
#pragma unroll
  for (int j = 0; j < 2; ++j) {
    const int q = j * 256 + t;
    const int i = q >> 4, c = q & 15;
    const float* fr = feat + (size_t)(r0 + i) * DF + c * 8;
    const short8v o = pack8(*reinterpret_cast<const float4*>(fr),
                            *reinterpret_cast<const float4*>(fr + 4));
    *reinterpret_cast<short8v*>(A + ((i * 256 + c * 16) ^ ((i & 7) << 4))) = o;
  }
  __syncthreads();

  const int w = t >> 6, l = t & 63, lr = l & 15, lg = l >> 4;
  const int sw = (lr & 7) << 4;
  const int row0 = lr, row1 = 16 + lr;
  f32x4 acc[2][2];
#pragma unroll
  for (int mt = 0; mt < 2; ++mt)
#pragma unroll
    for (int q = 0; q < 2; ++q)
#pragma unroll
      for (int r = 0; r < 4; ++r) acc[mt][q][r] = 0.f;
#pragma unroll
  for (int kt = 0; kt < 4; ++kt) {
    const short8v a0 = *reinterpret_cast<const short8v*>(
        A + ((row0 * 256 + kt * 64 + lg * 16) ^ sw));
    const short8v a1 = *reinterpret_cast<const short8v*>(
        A + ((row1 * 256 + kt * 64 + lg * 16) ^ sw));
#pragma unroll
    for (int q = 0; q < 2; ++q) {
      const short8v bq = *reinterpret_cast<const short8v*>(
          wp + (((size_t)(kt * 8 + 2 * w + q) * 64 + l) << 3));
      acc[0][q] = __builtin_amdgcn_mfma_f32_16x16x32_bf16(a0, bq, acc[0][q], 0, 0, 0);
      acc[1][q] = __builtin_amdgcn_mfma_f32_16x16x32_bf16(a1, bq, acc[1][q], 0, 0, 0);
    }
  }
#pragma unroll
  for (int q = 0; q < 2; ++q) {
    const int col = (2 * w + q) * 16 + lr;
    const float bias = b1[col];
#pragma unroll
    for (int mt = 0; mt < 2; ++mt)
#pragma unroll
      for (int r = 0; r < 4; ++r) {
        const int row = mt * 16 + lg * 4 + r;
        hid[row][col] = fmaxf(acc[mt][q][r] + bias, 0.f);
      }
  }
  __syncthreads();
  for (int o = t; o < 32 * TT; o += 256) {
    const int r = o / TT, c = o - TT * r;
    float s = b2[c];
    for (int k = 0; k < DF; ++k) s = fmaf(hid[r][k], w2s[k * TT + c], s);
    out[(size_t)(r0 + r) * TT + c] = s;
  }
}

// ---------------------------------------------------------------------------
extern "C" void kernel_launch(void* const* d_in, const int* in_sizes, int n_in,
                              void* d_out, int out_size, void* d_ws,
                              size_t ws_size, hipStream_t stream) {
  (void)in_sizes; (void)n_in; (void)out_size; (void)ws_size;
  const float* x         = (const float*)d_in[0];
  const float* edge_attr = (const float*)d_in[1];
  const int*   edge_idx  = (const int*)d_in[2];
  const int*   node_ty   = (const int*)d_in[3];
  const float* ne_w1 = (const float*)d_in[4];
  const float* ne_b1 = (const float*)d_in[5];
  const float* ne_w2 = (const float*)d_in[6];
  const float* ne_b2 = (const float*)d_in[7];
  const float* ee_w1 = (const float*)d_in[8];
  const float* ee_b1 = (const float*)d_in[9];
  const float* ee_w2 = (const float*)d_in[10];
  const float* ee_b2 = (const float*)d_in[11];
  const float* me_w1 = (const float*)d_in[12];
  const float* me_b1 = (const float*)d_in[13];
  const float* me_w2 = (const float*)d_in[14];
  const float* me_b2 = (const float*)d_in[15];
  const float* mn_w1 = (const float*)d_in[16];
  const float* mn_b1 = (const float*)d_in[17];
  const float* ec_w1 = (const float*)d_in[18];
  const float* ec_b1 = (const float*)d_in[19];
  const float* ec_w2 = (const float*)d_in[20];
  const float* ec_b2 = (const float*)d_in[21];
  const float* nc_w1 = (const float*)d_in[22];
  const float* nc_b1 = (const float*)d_in[23];
  const float* nc_w2 = (const float*)d_in[24];
  const float* nc_b2 = (const float*)d_in[25];
  const float* cc_w1 = (const float*)d_in[26];
  const float* cc_b1 = (const float*)d_in[27];
  const float* cc_w2 = (const float*)d_in[28];
  const float* cc_b2 = (const float*)d_in[29];

  const int* srcv = edge_idx;
  const int* dstv = edge_idx + N_EDGES;

  // ---- workspace layout ----
  float* agg = (float*)d_ws;                               // 2.56M f
  unsigned short* nf0b = (unsigned short*)(agg + (size_t)N_NODES * DF);
  unsigned short* nf1b = nf0b + (size_t)N_NODES * DF;
  unsigned short* ef0b = nf1b + (size_t)N_NODES * DF;
  unsigned short* ef1b = ef0b + (size_t)N_EDGES * DF;
  unsigned short* wme1 = ef1b + (size_t)N_EDGES * DF;      // 768x256
  unsigned short* wme2 = wme1 + 768 * 256;                 // 256x128
  unsigned short* wmn  = wme2 + 256 * 128;                 // 384x128
  unsigned short* wne1 = wmn + 384 * 128;                  // 17 x 256x128
  unsigned short* wne2 = wne1 + (size_t)TT * 256 * 128;    // 17 x 128x128
  unsigned short* wee1 = wne2 + (size_t)TT * 128 * 128;    // 64x128
  unsigned short* wee2 = wee1 + 64 * 128;                  // 128x128
  unsigned short* wec  = wee2 + 128 * 128;
  unsigned short* wnc  = wec + 128 * 128;
  unsigned short* wcc  = wnc + 128 * 128;
  int* cnt    = (int*)(wcc + 128 * 128);
  int* poff   = cnt + 32;
  int* woff   = poff + 32;
  int* bucket = woff + 32;                                 // 20544 ints

  // ---- output layout ----
  float* out_pe = (float*)d_out;
  float* out_pn = out_pe + N_EDGES;
  float* out_pc = out_pn + N_NODES;
  float* out_nf = out_pc + (size_t)N_NODES * TT;
  float* out_ef = out_nf + (size_t)N_NODES * DF;

  // ---- weight packing ----
  k_pack_w<<<96, 256, 0, stream>>>(me_w1, wme1, 768, 256, 1);
  k_pack_w<<<16, 256, 0, stream>>>(me_w2, wme2, 256, 128, 1);
  k_pack_w<<<24, 256, 0, stream>>>(mn_w1, wmn, 384, 128, 1);
  k_pack_w<<<272, 256, 0, stream>>>(ne_w1, wne1, 256, 128, TT);
  k_pack_w<<<136, 256, 0, stream>>>(ne_w2, wne2, 128, 128, TT);
  k_pack_w<<<4, 256, 0, stream>>>(ee_w1, wee1, 64, 128, 1);
  k_pack_w<<<8, 256, 0, stream>>>(ee_w2, wee2, 128, 128, 1);
  k_pack_w<<<8, 256, 0, stream>>>(ec_w1, wec, 128, 128, 1);
  k_pack_w<<<8, 256, 0, stream>>>(nc_w1, wnc, 128, 128, 1);
  k_pack_w<<<8, 256, 0, stream>>>(cc_w1, wcc, 128, 128, 1);

  // ---- type bucketing ----
  hipMemsetAsync(cnt, 0, 32 * sizeof(int), stream);
  hipMemsetAsync(bucket, 0xFF, NE_PAD_SLOTS * sizeof(int), stream);
  k_count<<<(N_NODES + 255) / 256, 256, 0, stream>>>(node_ty, cnt);
  k_prefix<<<1, 64, 0, stream>>>(cnt, poff, woff);
  k_scatter<<<(N_NODES + 255) / 256, 256, 0, stream>>>(node_ty, woff, bucket);

  // ---- embeddings ----
  k_node_embed_mfma<<<NE_PAD_SLOTS / 32, 256, 0, stream>>>(
      x, bucket, node_ty, wne1, ne_b1, wne2, ne_b2, nf0b);
  k_edge_embed_mfma<<<N_EDGES / 32, 256, 0, stream>>>(edge_attr, wee1, ee_b1,
                                                      wee2, ee_b2, ef0b);

  // ---- mp step 1 ----
  hipMemsetAsync(agg, 0, (size_t)N_NODES * DF * sizeof(float), stream);
  k_edge_mlp_mfma<false><<<N_EDGES / 128, 512, 0, stream>>>(
      nf0b, nf0b, ef0b, ef0b, (void*)ef1b, agg, srcv, dstv, wme1, me_b1, wme2, me_b2);
  k_node_update_mfma<false><<<N_NODES / 32, 256, 0, stream>>>(
      nf0b, nf0b, agg, (void*)nf1b, wmn, mn_b1);
  // ---- mp step 2 ----
  hipMemsetAsync(agg, 0, (size_t)N_NODES * DF * sizeof(float), stream);
  k_edge_mlp_mfma<false><<<N_EDGES / 128, 512, 0, stream>>>(
      nf0b, nf1b, ef0b, ef1b, (void*)ef1b, agg, srcv, dstv, wme1, me_b1, wme2, me_b2);
  k_node_update_mfma<false><<<N_NODES / 32, 256, 0, stream>>>(
      nf0b, nf1b, agg, (void*)nf1b, wmn, mn_b1);
  // pred_edge from ef after 2 steps
  k_cls_scalar_mfma<true><<<N_EDGES / 32, 256, 0, stream>>>(
      (const void*)ef1b, wec, ec_b1, ec_w2, ec_b2, out_pe);
  // ---- mp step 3 ----
  hipMemsetAsync(agg, 0, (size_t)N_NODES * DF * sizeof(float), stream);
  k_edge_mlp_mfma<true><<<N_EDGES / 128, 512, 0, stream>>>(
      nf0b, nf1b, ef0b, ef1b, (void*)out_ef, agg, srcv, dstv, wme1, me_b1, wme2, me_b2);
  k_node_update_mfma<true><<<N_NODES / 32, 256, 0, stream>>>(
      nf0b, nf1b, agg, (void*)out_nf, wmn, mn_b1);

  // ---- heads ----
  k_cls_scalar_mfma<false><<<N_NODES / 32, 256, 0, stream>>>(
      (const void*)out_nf, wnc, nc_b1, nc_w2, nc_b2, out_pn);
  k_cls_class_mfma<<<N_NODES / 32, 256, 0, stream>>>(out_nf, wcc, cc_b1, cc_w2,
                                                     cc_b2, out_pc);
}

// Round 5
// 687.801 us; speedup vs baseline: 1.3680x; 1.3680x over previous
//
#include <hip/hip_runtime.h>
#include <hip/hip_bf16.h>

#define N_NODES 20000
#define N_EDGES 160000
#define DIN_NODE 256
#define DIN_EDGE 64
#define DF 128      // feature dim
#define HH 256      // edge-MLP hidden dim
#define TT 17       // node types
#define NE_PAD_SLOTS 20544   // 642 blocks * 32 (type-padded bucket list)

typedef __attribute__((ext_vector_type(8))) short short8v;   // 8 bf16
typedef __attribute__((ext_vector_type(4))) float f32x4;     // MFMA C/D frag

// fp32 -> bf16 round-to-nearest-even
__device__ __forceinline__ unsigned short f2bf(float f) {
  unsigned int u = __builtin_bit_cast(unsigned int, f);
  u += 0x7FFFu + ((u >> 16) & 1u);
  return (unsigned short)(u >> 16);
}

__device__ __forceinline__ short8v pack8(float4 a, float4 b) {
  short8v o;
  o[0] = (short)f2bf(a.x); o[1] = (short)f2bf(a.y);
  o[2] = (short)f2bf(a.z); o[3] = (short)f2bf(a.w);
  o[4] = (short)f2bf(b.x); o[5] = (short)f2bf(b.y);
  o[6] = (short)f2bf(b.z); o[7] = (short)f2bf(b.w);
  return o;
}

// ---------------------------------------------------------------------------
// Pack fp32 weight [batch][K][N] into MFMA B-fragment order:
// tile = b*(K/32)*(N/16) + kt*(N/16) + nt; elem j of lane l =
// W[b][kt*32 + 8*(l>>4) + j][nt*16 + (l&15)].
// ---------------------------------------------------------------------------
__global__ __launch_bounds__(256) void k_pack_w(
    const float* __restrict__ w, unsigned short* __restrict__ out,
    int Kdim, int Ndim, int batch) {
  const int tile = blockIdx.x * 4 + (threadIdx.x >> 6);
  const int l = threadIdx.x & 63;
  const int ntTiles = Ndim >> 4;
  const int tilesPer = (Kdim >> 5) * ntTiles;
  if (tile >= tilesPer * batch) return;
  const int bt = tile / tilesPer;
  const int rr = tile - bt * tilesPer;
  const int kt = rr / ntTiles, nt = rr % ntTiles;
  const float* wb = w + (size_t)bt * Kdim * Ndim;
  const int col = (nt << 4) + (l & 15);
  const int k0 = (kt << 5) + ((l >> 4) << 3);
  unsigned short* o = out + (((size_t)tile << 6) + l) * 8;
#pragma unroll
  for (int j = 0; j < 8; ++j) o[j] = f2bf(wb[(size_t)(k0 + j) * Ndim + col]);
}

// ---------------------------------------------------------------------------
// Node-type bucketing (padded segments, 32-aligned per type).
// ---------------------------------------------------------------------------
__global__ void k_count(const int* __restrict__ types, int* __restrict__ cnt) {
  const int n = blockIdx.x * 256 + threadIdx.x;
  if (n < N_NODES) atomicAdd(&cnt[types[n]], 1);
}
__global__ void k_prefix(const int* __restrict__ cnt, int* __restrict__ poff,
                         int* __restrict__ woff) {
  if (threadIdx.x == 0) {
    int cur = 0;
    for (int t = 0; t < TT; ++t) {
      poff[t] = cur; woff[t] = cur;
      cur += (cnt[t] + 31) & ~31;
    }
  }
}
__global__ void k_scatter(const int* __restrict__ types, int* __restrict__ woff,
                          int* __restrict__ bucket) {
  const int n = blockIdx.x * 256 + threadIdx.x;
  if (n < N_NODES) {
    const int pos = atomicAdd(&woff[types[n]], 1);
    bucket[pos] = n;
  }
}

// ---------------------------------------------------------------------------
// Type-batched node embedding: 32 nodes of ONE type per block.
// ---------------------------------------------------------------------------
__global__ __launch_bounds__(256) void k_node_embed_mfma(
    const float* __restrict__ x, const int* __restrict__ bucket,
    const int* __restrict__ types,
    const unsigned short* __restrict__ wp1, const float* __restrict__ b1,
    const unsigned short* __restrict__ wp2, const float* __restrict__ b2,
    unsigned short* __restrict__ nf0b) {
  __shared__ __align__(16) unsigned char A[32 * 512];   // 32 x 256 bf16
  __shared__ __align__(16) unsigned char Hb[32 * 256];  // 32 x 128 bf16
  __shared__ int sn[32];
  const int t = threadIdx.x;
  const int r0 = blockIdx.x * 32;
  if (t < 32) sn[t] = bucket[r0 + t];
  __syncthreads();
  if (sn[0] < 0) return;          // whole window is padding
  const int ty = types[sn[0]];

#pragma unroll
  for (int j = 0; j < 4; ++j) {
    const int q = j * 256 + t;
    const int i = q >> 5, c = q & 31;
    const int nd = sn[i];
    short8v o;
    if (nd >= 0) {
      const float* xr = x + (size_t)nd * DIN_NODE + c * 8;
      o = pack8(*reinterpret_cast<const float4*>(xr),
                *reinterpret_cast<const float4*>(xr + 4));
    } else {
#pragma unroll
      for (int k = 0; k < 8; ++k) o[k] = 0;
    }
    *reinterpret_cast<short8v*>(A + ((i * 512 + c * 16) ^ ((i & 7) << 4))) = o;
  }
  __syncthreads();

  const int w = t >> 6, l = t & 63, lr = l & 15, lg = l >> 4;
  const int sw = (lr & 7) << 4;
  const int row0 = lr, row1 = 16 + lr;

  f32x4 acc[2][2];
#pragma unroll
  for (int mt = 0; mt < 2; ++mt)
#pragma unroll
    for (int q = 0; q < 2; ++q)
#pragma unroll
      for (int r = 0; r < 4; ++r) acc[mt][q][r] = 0.f;

#pragma unroll
  for (int kt = 0; kt < 8; ++kt) {
    const short8v a0 = *reinterpret_cast<const short8v*>(
        A + ((row0 * 512 + kt * 64 + lg * 16) ^ sw));
    const short8v a1 = *reinterpret_cast<const short8v*>(
        A + ((row1 * 512 + kt * 64 + lg * 16) ^ sw));
#pragma unroll
    for (int q = 0; q < 2; ++q) {
      const short8v bq = *reinterpret_cast<const short8v*>(
          wp1 + (((size_t)(ty * 64 + kt * 8 + 2 * w + q) * 64 + l) << 3));
      acc[0][q] = __builtin_amdgcn_mfma_f32_16x16x32_bf16(a0, bq, acc[0][q], 0, 0, 0);
      acc[1][q] = __builtin_amdgcn_mfma_f32_16x16x32_bf16(a1, bq, acc[1][q], 0, 0, 0);
    }
  }
#pragma unroll
  for (int q = 0; q < 2; ++q) {
    const int col = (2 * w + q) * 16 + lr;
    const float bias = b1[ty * DF + col];
#pragma unroll
    for (int mt = 0; mt < 2; ++mt)
#pragma unroll
      for (int r = 0; r < 4; ++r) {
        const int row = mt * 16 + lg * 4 + r;
        *reinterpret_cast<unsigned short*>(
            Hb + ((row * 256 + col * 2) ^ ((row & 7) << 4))) =
            f2bf(fmaxf(acc[mt][q][r] + bias, 0.f));
      }
  }
  __syncthreads();

  f32x4 acc2[2][2];
#pragma unroll
  for (int mt = 0; mt < 2; ++mt)
#pragma unroll
    for (int q = 0; q < 2; ++q)
#pragma unroll
      for (int r = 0; r < 4; ++r) acc2[mt][q][r] = 0.f;
#pragma unroll
  for (int kt = 0; kt < 4; ++kt) {
    const short8v a0 = *reinterpret_cast<const short8v*>(
        Hb + ((row0 * 256 + kt * 64 + lg * 16) ^ sw));
    const short8v a1 = *reinterpret_cast<const short8v*>(
        Hb + ((row1 * 256 + kt * 64 + lg * 16) ^ sw));
#pragma unroll
    for (int q = 0; q < 2; ++q) {
      const short8v bq = *reinterpret_cast<const short8v*>(
          wp2 + (((size_t)(ty * 32 + kt * 8 + 2 * w + q) * 64 + l) << 3));
      acc2[0][q] = __builtin_amdgcn_mfma_f32_16x16x32_bf16(a0, bq, acc2[0][q], 0, 0, 0);
      acc2[1][q] = __builtin_amdgcn_mfma_f32_16x16x32_bf16(a1, bq, acc2[1][q], 0, 0, 0);
    }
  }
#pragma unroll
  for (int q = 0; q < 2; ++q) {
    const int col = (2 * w + q) * 16 + lr;
    const float bias = b2[ty * DF + col];
#pragma unroll
    for (int mt = 0; mt < 2; ++mt)
#pragma unroll
      for (int r = 0; r < 4; ++r) {
        const int row = mt * 16 + lg * 4 + r;
        const int nd = sn[row];
        if (nd >= 0)
          nf0b[(size_t)nd * DF + col] = f2bf(acc2[mt][q][r] + bias);
      }
  }
}

// ---------------------------------------------------------------------------
// Edge embedding MFMA: 64 -> 128 relu -> 128, 32 edges/block, bf16 out.
// ---------------------------------------------------------------------------
__global__ __launch_bounds__(256) void k_edge_embed_mfma(
    const float* __restrict__ ea,
    const unsigned short* __restrict__ wp1, const float* __restrict__ b1,
    const unsigned short* __restrict__ wp2, const float* __restrict__ b2,
    unsigned short* __restrict__ ef0b) {
  __shared__ __align__(16) unsigned char A[32 * 128];   // 32 x 64 bf16
  __shared__ __align__(16) unsigned char Hb[32 * 256];  // 32 x 128 bf16
  const int t = threadIdx.x;
  const int e0 = blockIdx.x * 32;
  {
    const int i = t >> 3, c = t & 7;
    const float* xr = ea + (size_t)(e0 + i) * DIN_EDGE + c * 8;
    const short8v o = pack8(*reinterpret_cast<const float4*>(xr),
                            *reinterpret_cast<const float4*>(xr + 4));
    *reinterpret_cast<short8v*>(A + ((i * 128 + c * 16) ^ ((i & 7) << 4))) = o;
  }
  __syncthreads();

  const int w = t >> 6, l = t & 63, lr = l & 15, lg = l >> 4;
  const int sw = (lr & 7) << 4;
  const int row0 = lr, row1 = 16 + lr;

  f32x4 acc[2][2];
#pragma unroll
  for (int mt = 0; mt < 2; ++mt)
#pragma unroll
    for (int q = 0; q < 2; ++q)
#pragma unroll
      for (int r = 0; r < 4; ++r) acc[mt][q][r] = 0.f;
#pragma unroll
  for (int kt = 0; kt < 2; ++kt) {
    const short8v a0 = *reinterpret_cast<const short8v*>(
        A + ((row0 * 128 + kt * 64 + lg * 16) ^ sw));
    const short8v a1 = *reinterpret_cast<const short8v*>(
        A + ((row1 * 128 + kt * 64 + lg * 16) ^ sw));
#pragma unroll
    for (int q = 0; q < 2; ++q) {
      const short8v bq = *reinterpret_cast<const short8v*>(
          wp1 + (((size_t)(kt * 8 + 2 * w + q) * 64 + l) << 3));
      acc[0][q] = __builtin_amdgcn_mfma_f32_16x16x32_bf16(a0, bq, acc[0][q], 0, 0, 0);
      acc[1][q] = __builtin_amdgcn_mfma_f32_16x16x32_bf16(a1, bq, acc[1][q], 0, 0, 0);
    }
  }
#pragma unroll
  for (int q = 0; q < 2; ++q) {
    const int col = (2 * w + q) * 16 + lr;
    const float bias = b1[col];
#pragma unroll
    for (int mt = 0; mt < 2; ++mt)
#pragma unroll
      for (int r = 0; r < 4; ++r) {
        const int row = mt * 16 + lg * 4 + r;
        *reinterpret_cast<unsigned short*>(
            Hb + ((row * 256 + col * 2) ^ ((row & 7) << 4))) =
            f2bf(fmaxf(acc[mt][q][r] + bias, 0.f));
      }
  }
  __syncthreads();

  f32x4 acc2[2][2];
#pragma unroll
  for (int mt = 0; mt < 2; ++mt)
#pragma unroll
    for (int q = 0; q < 2; ++q)
#pragma unroll
      for (int r = 0; r < 4; ++r) acc2[mt][q][r] = 0.f;
#pragma unroll
  for (int kt = 0; kt < 4; ++kt) {
    const short8v a0 = *reinterpret_cast<const short8v*>(
        Hb + ((row0 * 256 + kt * 64 + lg * 16) ^ sw));
    const short8v a1 = *reinterpret_cast<const short8v*>(
        Hb + ((row1 * 256 + kt * 64 + lg * 16) ^ sw));
#pragma unroll
    for (int q = 0; q < 2; ++q) {
      const short8v bq = *reinterpret_cast<const short8v*>(
          wp2 + (((size_t)(kt * 8 + 2 * w + q) * 64 + l) << 3));
      acc2[0][q] = __builtin_amdgcn_mfma_f32_16x16x32_bf16(a0, bq, acc2[0][q], 0, 0, 0);
      acc2[1][q] = __builtin_amdgcn_mfma_f32_16x16x32_bf16(a1, bq, acc2[1][q], 0, 0, 0);
    }
  }
#pragma unroll
  for (int q = 0; q < 2; ++q) {
    const int col = (2 * w + q) * 16 + lr;
    const float bias = b2[col];
#pragma unroll
    for (int mt = 0; mt < 2; ++mt)
#pragma unroll
      for (int r = 0; r < 4; ++r) {
        const int row = mt * 16 + lg * 4 + r;
        ef0b[(size_t)(e0 + row) * DF + col] = f2bf(acc2[mt][q][r] + bias);
      }
  }
}

// ---------------------------------------------------------------------------
// Edge MLP via MFMA v4: 32 edges/block, 4 waves (v2 structure), with explicit
// depth-2 software pipeline on A (ds_read) and B (global, L2-hit) fragments.
// ---------------------------------------------------------------------------
template <bool OUTF>
__global__ __launch_bounds__(256) void k_edge_mlp_mfma(
    const unsigned short* __restrict__ nf0, const unsigned short* __restrict__ nf,
    const unsigned short* __restrict__ ef0, const unsigned short* __restrict__ ef_in,
    void* __restrict__ ef_out, float* __restrict__ agg,
    const int* __restrict__ srcv, const int* __restrict__ dstv,
    const unsigned short* __restrict__ wp1, const float* __restrict__ b1,
    const unsigned short* __restrict__ wp2, const float* __restrict__ b2) {
  __shared__ __align__(16) unsigned char A_lds[32 * 768 * 2];  // 48 KB
  __shared__ int sd[2][32];
  const int t = threadIdx.x;
  const int e0 = blockIdx.x * 32;
  if (t < 32) sd[0][t] = srcv[e0 + t];
  else if (t < 64) sd[1][t - 32] = dstv[e0 + t - 32];
  __syncthreads();

  // gather bf16: 3072 chunks of 16B
#pragma unroll
  for (int j = 0; j < 12; ++j) {
    const int q = j * 256 + t;
    const int c = q & 15;
    const int seg = q >> 4;
    const int i = seg / 6;
    const int p = seg - 6 * i;
    const unsigned short* bp;
    switch (p) {
      case 0: bp = nf0 + (size_t)sd[1][i] * DF; break;
      case 1: bp = nf + (size_t)sd[1][i] * DF; break;
      case 2: bp = nf0 + (size_t)sd[0][i] * DF; break;
      case 3: bp = nf + (size_t)sd[0][i] * DF; break;
      case 4: bp = ef0 + (size_t)(e0 + i) * DF; break;
      default: bp = ef_in + (size_t)(e0 + i) * DF; break;
    }
    const short8v v = *reinterpret_cast<const short8v*>(bp + c * 8);
    *reinterpret_cast<short8v*>(
        A_lds + ((i * 1536 + p * 256 + c * 16) ^ ((i & 7) << 4))) = v;
  }
  __syncthreads();

  const int w = t >> 6, l = t & 63, lr = l & 15, lg = l >> 4;
  const int swz = (lr & 7) << 4;   // same for row lr and row 16+lr

  // ---- layer 1: [32x768] @ [768x256], wave w owns n-tiles 4w..4w+3 ---------
  f32x4 acc[2][4];
#pragma unroll
  for (int mt = 0; mt < 2; ++mt)
#pragma unroll
    for (int q = 0; q < 4; ++q)
#pragma unroll
      for (int r = 0; r < 4; ++r) acc[mt][q][r] = 0.f;

  const int r0o = lr * 1536 + lg * 16;
  const int r1o = (16 + lr) * 1536 + lg * 16;
  const unsigned short* wb1 = wp1 + (((size_t)(4 * w) * 64 + l) << 3);
  // per-kt stride in ushorts: 16 tiles * 512 = 8192; per-q stride: 512

  short8v aR[3][2], bR[3][4];
#pragma unroll
  for (int s = 0; s < 2; ++s) {
    aR[s][0] = *reinterpret_cast<const short8v*>(A_lds + ((r0o + s * 64) ^ swz));
    aR[s][1] = *reinterpret_cast<const short8v*>(A_lds + ((r1o + s * 64) ^ swz));
#pragma unroll
    for (int q = 0; q < 4; ++q)
      bR[s][q] = *reinterpret_cast<const short8v*>(wb1 + (size_t)s * 8192 + q * 512);
  }
#pragma unroll
  for (int kt = 0; kt < 24; ++kt) {
    const int cur = kt % 3, pf = (kt + 2) % 3;
    if (kt < 22) {
      aR[pf][0] = *reinterpret_cast<const short8v*>(
          A_lds + ((r0o + (kt + 2) * 64) ^ swz));
      aR[pf][1] = *reinterpret_cast<const short8v*>(
          A_lds + ((r1o + (kt + 2) * 64) ^ swz));
#pragma unroll
      for (int q = 0; q < 4; ++q)
        bR[pf][q] = *reinterpret_cast<const short8v*>(
            wb1 + (size_t)(kt + 2) * 8192 + q * 512);
    }
#pragma unroll
    for (int q = 0; q < 4; ++q) {
      acc[0][q] = __builtin_amdgcn_mfma_f32_16x16x32_bf16(aR[cur][0], bR[cur][q],
                                                          acc[0][q], 0, 0, 0);
      acc[1][q] = __builtin_amdgcn_mfma_f32_16x16x32_bf16(aR[cur][1], bR[cur][q],
                                                          acc[1][q], 0, 0, 0);
    }
  }
  __syncthreads();   // everyone done reading A_lds

  // hidden (bias+relu) -> bf16 [32][256] swizzled, reuses A_lds
#pragma unroll
  for (int q = 0; q < 4; ++q) {
    const int col = (4 * w + q) * 16 + lr;
    const float bias = b1[col];
#pragma unroll
    for (int mt = 0; mt < 2; ++mt)
#pragma unroll
      for (int r = 0; r < 4; ++r) {
        const int row = mt * 16 + lg * 4 + r;
        *reinterpret_cast<unsigned short*>(
            A_lds + ((row * 512 + col * 2) ^ ((row & 7) << 4))) =
            f2bf(fmaxf(acc[mt][q][r] + bias, 0.f));
      }
  }
  __syncthreads();

  // ---- layer 2: [32x256] @ [256x128], wave w owns n-tiles 2w, 2w+1 ---------
  f32x4 acc2[2][2];
#pragma unroll
  for (int mt = 0; mt < 2; ++mt)
#pragma unroll
    for (int q = 0; q < 2; ++q)
#pragma unroll
      for (int r = 0; r < 4; ++r) acc2[mt][q][r] = 0.f;

  const int h0o = lr * 512 + lg * 16;
  const int h1o = (16 + lr) * 512 + lg * 16;
  const unsigned short* wb2 = wp2 + (((size_t)(2 * w) * 64 + l) << 3);
  // per-kt stride in ushorts: 8 tiles * 512 = 4096

  short8v aS[3][2], bS[3][2];
#pragma unroll
  for (int s = 0; s < 2; ++s) {
    aS[s][0] = *reinterpret_cast<const short8v*>(A_lds + ((h0o + s * 64) ^ swz));
    aS[s][1] = *reinterpret_cast<const short8v*>(A_lds + ((h1o + s * 64) ^ swz));
#pragma unroll
    for (int q = 0; q < 2; ++q)
      bS[s][q] = *reinterpret_cast<const short8v*>(wb2 + (size_t)s * 4096 + q * 512);
  }
#pragma unroll
  for (int kt = 0; kt < 8; ++kt) {
    const int cur = kt % 3, pf = (kt + 2) % 3;
    if (kt < 6) {
      aS[pf][0] = *reinterpret_cast<const short8v*>(
          A_lds + ((h0o + (kt + 2) * 64) ^ swz));
      aS[pf][1] = *reinterpret_cast<const short8v*>(
          A_lds + ((h1o + (kt + 2) * 64) ^ swz));
#pragma unroll
      for (int q = 0; q < 2; ++q)
        bS[pf][q] = *reinterpret_cast<const short8v*>(
            wb2 + (size_t)(kt + 2) * 4096 + q * 512);
    }
#pragma unroll
    for (int q = 0; q < 2; ++q) {
      acc2[0][q] = __builtin_amdgcn_mfma_f32_16x16x32_bf16(aS[cur][0], bS[cur][q],
                                                           acc2[0][q], 0, 0, 0);
      acc2[1][q] = __builtin_amdgcn_mfma_f32_16x16x32_bf16(aS[cur][1], bS[cur][q],
                                                           acc2[1][q], 0, 0, 0);
    }
  }

  // ---- epilogue: bias, store ef, atomic agg[dst] ---------------------------
#pragma unroll
  for (int q = 0; q < 2; ++q) {
    const int n = (2 * w + q) * 16 + lr;
    const float bias = b2[n];
#pragma unroll
    for (int mt = 0; mt < 2; ++mt)
#pragma unroll
      for (int r = 0; r < 4; ++r) {
        const int m = mt * 16 + lg * 4 + r;
        const float v = acc2[mt][q][r] + bias;
        if (OUTF)
          ((float*)ef_out)[(size_t)(e0 + m) * DF + n] = v;
        else
          ((unsigned short*)ef_out)[(size_t)(e0 + m) * DF + n] = f2bf(v);
        atomicAdd(&agg[(size_t)sd[1][m] * DF + n], v);
      }
  }
}

// ---------------------------------------------------------------------------
// Node update MFMA: [nf0|nf|agg] (384) @ w + b, 32 nodes/block.
// ---------------------------------------------------------------------------
template <bool OUTF>
__global__ __launch_bounds__(256) void k_node_update_mfma(
    const unsigned short* __restrict__ nf0, const unsigned short* __restrict__ nfb,
    const float* __restrict__ agg, void* __restrict__ outp,
    const unsigned short* __restrict__ wp, const float* __restrict__ b) {
  __shared__ __align__(16) unsigned char A[32 * 768];   // 32 x 384 bf16
  const int t = threadIdx.x;
  const int n0 = blockIdx.x * 32;
#pragma unroll
  for (int j = 0; j < 6; ++j) {
    const int q = j * 256 + t;
    const int i = q / 48;
    const int cc = q - i * 48;
    const int p = cc >> 4, c = cc & 15;
    const int row = n0 + i;
    short8v o;
    if (p == 0)
      o = *reinterpret_cast<const short8v*>(nf0 + (size_t)row * DF + c * 8);
    else if (p == 1)
      o = *reinterpret_cast<const short8v*>(nfb + (size_t)row * DF + c * 8);
    else {
      const float* ar = agg + (size_t)row * DF + c * 8;
      o = pack8(*reinterpret_cast<const float4*>(ar),
                *reinterpret_cast<const float4*>(ar + 4));
    }
    *reinterpret_cast<short8v*>(
        A + ((i * 768 + p * 256 + c * 16) ^ ((i & 7) << 4))) = o;
  }
  __syncthreads();

  const int w = t >> 6, l = t & 63, lr = l & 15, lg = l >> 4;
  const int sw = (lr & 7) << 4;
  const int row0 = lr, row1 = 16 + lr;

  f32x4 acc[2][2];
#pragma unroll
  for (int mt = 0; mt < 2; ++mt)
#pragma unroll
    for (int q = 0; q < 2; ++q)
#pragma unroll
      for (int r = 0; r < 4; ++r) acc[mt][q][r] = 0.f;
#pragma unroll
  for (int kt = 0; kt < 12; ++kt) {
    const short8v a0 = *reinterpret_cast<const short8v*>(
        A + ((row0 * 768 + kt * 64 + lg * 16) ^ sw));
    const short8v a1 = *reinterpret_cast<const short8v*>(
        A + ((row1 * 768 + kt * 64 + lg * 16) ^ sw));
#pragma unroll
    for (int q = 0; q < 2; ++q) {
      const short8v bq = *reinterpret_cast<const short8v*>(
          wp + (((size_t)(kt * 8 + 2 * w + q) * 64 + l) << 3));
      acc[0][q] = __builtin_amdgcn_mfma_f32_16x16x32_bf16(a0, bq, acc[0][q], 0, 0, 0);
      acc[1][q] = __builtin_amdgcn_mfma_f32_16x16x32_bf16(a1, bq, acc[1][q], 0, 0, 0);
    }
  }
#pragma unroll
  for (int q = 0; q < 2; ++q) {
    const int col = (2 * w + q) * 16 + lr;
    const float bias = b[col];
#pragma unroll
    for (int mt = 0; mt < 2; ++mt)
#pragma unroll
      for (int r = 0; r < 4; ++r) {
        const int row = mt * 16 + lg * 4 + r;
        const float v = acc[mt][q][r] + bias;
        if (OUTF)
          ((float*)outp)[(size_t)(n0 + row) * DF + col] = v;
        else
          ((unsigned short*)outp)[(size_t)(n0 + row) * DF + col] = f2bf(v);
      }
  }
}

// ---------------------------------------------------------------------------
// Scalar classifier: relu(f @ w1 + b1) . w2 + b2, 32 rows/block.
// ---------------------------------------------------------------------------
template <bool INBF>
__global__ __launch_bounds__(256) void k_cls_scalar_mfma(
    const void* __restrict__ feat, const unsigned short* __restrict__ wp,
    const float* __restrict__ b1, const float* __restrict__ w2,
    const float* __restrict__ b2, float* __restrict__ out) {
  __shared__ __align__(16) unsigned char A[32 * 256];  // 32 x 128 bf16
  __shared__ float hid[32][136];
  __shared__ float w2s[DF];
  __shared__ float part[32][8];
  const int t = threadIdx.x;
  const int r0 = blockIdx.x * 32;
  if (t < DF) w2s[t] = w2[t];
#pragma unroll
  for (int j = 0; j < 2; ++j) {
    const int q = j * 256 + t;
    const int i = q >> 4, c = q & 15;
    short8v o;
    if (INBF) {
      o = *reinterpret_cast<const short8v*>(
          (const unsigned short*)feat + (size_t)(r0 + i) * DF + c * 8);
    } else {
      const float* fr = (const float*)feat + (size_t)(r0 + i) * DF + c * 8;
      o = pack8(*reinterpret_cast<const float4*>(fr),
                *reinterpret_cast<const float4*>(fr + 4));
    }
    *reinterpret_cast<short8v*>(A + ((i * 256 + c * 16) ^ ((i & 7) << 4))) = o;
  }
  __syncthreads();

  const int w = t >> 6, l = t & 63, lr = l & 15, lg = l >> 4;
  const int sw = (lr & 7) << 4;
  const int row0 = lr, row1 = 16 + lr;
  f32x4 acc[2][2];
#pragma unroll
  for (int mt = 0; mt < 2; ++mt)
#pragma unroll
    for (int q = 0; q < 2; ++q)
#pragma unroll
      for (int r = 0; r < 4; ++r) acc[mt][q][r] = 0.f;
#pragma unroll
  for (int kt = 0; kt < 4; ++kt) {
    const short8v a0 = *reinterpret_cast<const short8v*>(
        A + ((row0 * 256 + kt * 64 + lg * 16) ^ sw));
    const short8v a1 = *reinterpret_cast<const short8v*>(
        A + ((row1 * 256 + kt * 64 + lg * 16) ^ sw));
#pragma unroll
    for (int q = 0; q < 2; ++q) {
      const short8v bq = *reinterpret_cast<const short8v*>(
          wp + (((size_t)(kt * 8 + 2 * w + q) * 64 + l) << 3));
      acc[0][q] = __builtin_amdgcn_mfma_f32_16x16x32_bf16(a0, bq, acc[0][q], 0, 0, 0);
      acc[1][q] = __builtin_amdgcn_mfma_f32_16x16x32_bf16(a1, bq, acc[1][q], 0, 0, 0);
    }
  }
#pragma unroll
  for (int q = 0; q < 2; ++q) {
    const int col = (2 * w + q) * 16 + lr;
    const float bias = b1[col];
#pragma unroll
    for (int mt = 0; mt < 2; ++mt)
#pragma unroll
      for (int r = 0; r < 4; ++r) {
        const int row = mt * 16 + lg * 4 + r;
        hid[row][col] = fmaxf(acc[mt][q][r] + bias, 0.f);
      }
  }
  __syncthreads();
  {
    const int r = t >> 3, kc = t & 7;
    float s = 0.f;
#pragma unroll
    for (int u = 0; u < 16; ++u) s = fmaf(hid[r][kc * 16 + u], w2s[kc * 16 + u], s);
    part[r][kc] = s;
  }
  __syncthreads();
  if (t < 32) {
    float s = b2[0];
#pragma unroll
    for (int k = 0; k < 8; ++k) s += part[t][k];
    out[r0 + t] = s;
  }
}

// ---------------------------------------------------------------------------
// Class classifier: relu(f @ w1 + b1) @ w2[128,17] + b2, fp32 input.
// ---------------------------------------------------------------------------
__global__ __launch_bounds__(256) void k_cls_class_mfma(
    const float* __restrict__ feat, const unsigned short* __restrict__ wp,
    const float* __restrict__ b1, const float* __restrict__ w2,
    const float* __restrict__ b2, float* __restrict__ out) {
  __shared__ __align__(16) unsigned char A[32 * 256];
  __shared__ float hid[32][136];
  __shared__ float w2s[DF * TT];
  const int t = threadIdx.x;
  const int r0 = blockIdx.x * 32;
  for (int j = t; j < DF * TT; j += 256) w2s[j] = w2[j];
#pragma unroll
  for (int j = 0; j < 2; ++j) {
    const int q = j * 256 + t;
    const int i = q >> 4, c = q & 15;
    const float* fr = feat + (size_t)(r0 + i) * DF + c * 8;
    const short8v o = pack8(*reinterpret_cast<const float4*>(fr),
                            *reinterpret_cast<const float4*>(fr + 4));
    *reinterpret_cast<short8v*>(A + ((i * 256 + c * 16) ^ ((i & 7) << 4))) = o;
  }
  __syncthreads();

  const int w = t >> 6, l = t & 63, lr = l & 15, lg = l >> 4;
  const int sw = (lr & 7) << 4;
  const int row0 = lr, row1 = 16 + lr;
  f32x4 acc[2][2];
#pragma unroll
  for (int mt = 0; mt < 2; ++mt)
#pragma unroll
    for (int q = 0; q < 2; ++q)
#pragma unroll
      for (int r = 0; r < 4; ++r) acc[mt][q][r] = 0.f;
#pragma unroll
  for (int kt = 0; kt < 4; ++kt) {
    const short8v a0 = *reinterpret_cast<const short8v*>(
        A + ((row0 * 256 + kt * 64 + lg * 16) ^ sw));
    const short8v a1 = *reinterpret_cast<const short8v*>(
        A + ((row1 * 256 + kt * 64 + lg * 16) ^ sw));
#pragma unroll
    for (int q = 0; q < 2; ++q) {
      const short8v bq = *reinterpret_cast<const short8v*>(
          wp + (((size_t)(kt * 8 + 2 * w + q) * 64 + l) << 3));
      acc[0][q] = __builtin_amdgcn_mfma_f32_16x16x32_bf16(a0, bq, acc[0][q], 0, 0, 0);
      acc[1][q] = __builtin_amdgcn_mfma_f32_16x16x32_bf16(a1, bq, acc[1][q], 0, 0, 0);
    }
  }
#pragma unroll
  for (int q = 0; q < 2; ++q) {
    const int col = (2 * w + q) * 16 + lr;
    const float bias = b1[col];
#pragma unroll
    for (int mt = 0; mt < 2; ++mt)
#pragma unroll
      for (int r = 0; r < 4; ++r) {
        const int row = mt * 16 + lg * 4 + r;
        hid[row][col] = fmaxf(acc[mt][q][r] + bias, 0.f);
      }
  }
  __syncthreads();
  for (int o = t; o < 32 * TT; o += 256) {
    const int r = o / TT, c = o - TT * r;
    float s = b2[c];
    for (int k = 0; k < DF; ++k) s = fmaf(hid[r][k], w2s[k * TT + c], s);
    out[(size_t)(r0 + r) * TT + c] = s;
  }
}

// ---------------------------------------------------------------------------
extern "C" void kernel_launch(void* const* d_in, const int* in_sizes, int n_in,
                              void* d_out, int out_size, void* d_ws,
                              size_t ws_size, hipStream_t stream) {
  (void)in_sizes; (void)n_in; (void)out_size; (void)ws_size;
  const float* x         = (const float*)d_in[0];
  const float* edge_attr = (const float*)d_in[1];
  const int*   edge_idx  = (const int*)d_in[2];
  const int*   node_ty   = (const int*)d_in[3];
  const float* ne_w1 = (const float*)d_in[4];
  const float* ne_b1 = (const float*)d_in[5];
  const float* ne_w2 = (const float*)d_in[6];
  const float* ne_b2 = (const float*)d_in[7];
  const float* ee_w1 = (const float*)d_in[8];
  const float* ee_b1 = (const float*)d_in[9];
  const float* ee_w2 = (const float*)d_in[10];
  const float* ee_b2 = (const float*)d_in[11];
  const float* me_w1 = (const float*)d_in[12];
  const float* me_b1 = (const float*)d_in[13];
  const float* me_w2 = (const float*)d_in[14];
  const float* me_b2 = (const float*)d_in[15];
  const float* mn_w1 = (const float*)d_in[16];
  const float* mn_b1 = (const float*)d_in[17];
  const float* ec_w1 = (const float*)d_in[18];
  const float* ec_b1 = (const float*)d_in[19];
  const float* ec_w2 = (const float*)d_in[20];
  const float* ec_b2 = (const float*)d_in[21];
  const float* nc_w1 = (const float*)d_in[22];
  const float* nc_b1 = (const float*)d_in[23];
  const float* nc_w2 = (const float*)d_in[24];
  const float* nc_b2 = (const float*)d_in[25];
  const float* cc_w1 = (const float*)d_in[26];
  const float* cc_b1 = (const float*)d_in[27];
  const float* cc_w2 = (const float*)d_in[28];
  const float* cc_b2 = (const float*)d_in[29];

  const int* srcv = edge_idx;
  const int* dstv = edge_idx + N_EDGES;

  // ---- workspace layout ----
  float* agg = (float*)d_ws;                               // 2.56M f
  unsigned short* nf0b = (unsigned short*)(agg + (size_t)N_NODES * DF);
  unsigned short* nf1b = nf0b + (size_t)N_NODES * DF;
  unsigned short* ef0b = nf1b + (size_t)N_NODES * DF;
  unsigned short* ef1b = ef0b + (size_t)N_EDGES * DF;
  unsigned short* wme1 = ef1b + (size_t)N_EDGES * DF;      // 768x256
  unsigned short* wme2 = wme1 + 768 * 256;                 // 256x128
  unsigned short* wmn  = wme2 + 256 * 128;                 // 384x128
  unsigned short* wne1 = wmn + 384 * 128;                  // 17 x 256x128
  unsigned short* wne2 = wne1 + (size_t)TT * 256 * 128;    // 17 x 128x128
  unsigned short* wee1 = wne2 + (size_t)TT * 128 * 128;    // 64x128
  unsigned short* wee2 = wee1 + 64 * 128;                  // 128x128
  unsigned short* wec  = wee2 + 128 * 128;
  unsigned short* wnc  = wec + 128 * 128;
  unsigned short* wcc  = wnc + 128 * 128;
  int* cnt    = (int*)(wcc + 128 * 128);
  int* poff   = cnt + 32;
  int* woff   = poff + 32;
  int* bucket = woff + 32;                                 // 20544 ints

  // ---- output layout ----
  float* out_pe = (float*)d_out;
  float* out_pn = out_pe + N_EDGES;
  float* out_pc = out_pn + N_NODES;
  float* out_nf = out_pc + (size_t)N_NODES * TT;
  float* out_ef = out_nf + (size_t)N_NODES * DF;

  // ---- weight packing ----
  k_pack_w<<<96, 256, 0, stream>>>(me_w1, wme1, 768, 256, 1);
  k_pack_w<<<16, 256, 0, stream>>>(me_w2, wme2, 256, 128, 1);
  k_pack_w<<<24, 256, 0, stream>>>(mn_w1, wmn, 384, 128, 1);
  k_pack_w<<<272, 256, 0, stream>>>(ne_w1, wne1, 256, 128, TT);
  k_pack_w<<<136, 256, 0, stream>>>(ne_w2, wne2, 128, 128, TT);
  k_pack_w<<<4, 256, 0, stream>>>(ee_w1, wee1, 64, 128, 1);
  k_pack_w<<<8, 256, 0, stream>>>(ee_w2, wee2, 128, 128, 1);
  k_pack_w<<<8, 256, 0, stream>>>(ec_w1, wec, 128, 128, 1);
  k_pack_w<<<8, 256, 0, stream>>>(nc_w1, wnc, 128, 128, 1);
  k_pack_w<<<8, 256, 0, stream>>>(cc_w1, wcc, 128, 128, 1);

  // ---- type bucketing ----
  hipMemsetAsync(cnt, 0, 32 * sizeof(int), stream);
  hipMemsetAsync(bucket, 0xFF, NE_PAD_SLOTS * sizeof(int), stream);
  k_count<<<(N_NODES + 255) / 256, 256, 0, stream>>>(node_ty, cnt);
  k_prefix<<<1, 64, 0, stream>>>(cnt, poff, woff);
  k_scatter<<<(N_NODES + 255) / 256, 256, 0, stream>>>(node_ty, woff, bucket);

  // ---- embeddings ----
  k_node_embed_mfma<<<NE_PAD_SLOTS / 32, 256, 0, stream>>>(
      x, bucket, node_ty, wne1, ne_b1, wne2, ne_b2, nf0b);
  k_edge_embed_mfma<<<N_EDGES / 32, 256, 0, stream>>>(edge_attr, wee1, ee_b1,
                                                      wee2, ee_b2, ef0b);

  // ---- mp step 1 ----
  hipMemsetAsync(agg, 0, (size_t)N_NODES * DF * sizeof(float), stream);
  k_edge_mlp_mfma<false><<<N_EDGES / 32, 256, 0, stream>>>(
      nf0b, nf0b, ef0b, ef0b, (void*)ef1b, agg, srcv, dstv, wme1, me_b1, wme2, me_b2);
  k_node_update_mfma<false><<<N_NODES / 32, 256, 0, stream>>>(
      nf0b, nf0b, agg, (void*)nf1b, wmn, mn_b1);
  // ---- mp step 2 ----
  hipMemsetAsync(agg, 0, (size_t)N_NODES * DF * sizeof(float), stream);
  k_edge_mlp_mfma<false><<<N_EDGES / 32, 256, 0, stream>>>(
      nf0b, nf1b, ef0b, ef1b, (void*)ef1b, agg, srcv, dstv, wme1, me_b1, wme2, me_b2);
  k_node_update_mfma<false><<<N_NODES / 32, 256, 0, stream>>>(
      nf0b, nf1b, agg, (void*)nf1b, wmn, mn_b1);
  // pred_edge from ef after 2 steps
  k_cls_scalar_mfma<true><<<N_EDGES / 32, 256, 0, stream>>>(
      (const void*)ef1b, wec, ec_b1, ec_w2, ec_b2, out_pe);
  // ---- mp step 3 ----
  hipMemsetAsync(agg, 0, (size_t)N_NODES * DF * sizeof(float), stream);
  k_edge_mlp_mfma<true><<<N_EDGES / 32, 256, 0, stream>>>(
      nf0b, nf1b, ef0b, ef1b, (void*)out_ef, agg, srcv, dstv, wme1, me_b1, wme2, me_b2);
  k_node_update_mfma<true><<<N_NODES / 32, 256, 0, stream>>>(
      nf0b, nf1b, agg, (void*)out_nf, wmn, mn_b1);

  // ---- heads ----
  k_cls_scalar_mfma<false><<<N_NODES / 32, 256, 0, stream>>>(
      (const void*)out_nf, wnc, nc_b1, nc_w2, nc_b2, out_pn);
  k_cls_class_mfma<<<N_NODES / 32, 256, 0, stream>>>(out_nf, wcc, cc_b1, cc_w2,
                                                     cc_b2, out_pc);
}

// Round 6
// 633.110 us; speedup vs baseline: 1.4862x; 1.0864x over previous
//
#include <hip/hip_runtime.h>
#include <hip/hip_bf16.h>

#define N_NODES 20000
#define N_EDGES 160000
#define DIN_NODE 256
#define DIN_EDGE 64
#define DF 128      // feature dim
#define HH 256      // edge-MLP hidden dim
#define TT 17       // node types
#define NE_PAD_SLOTS 20544   // 642 blocks * 32 (type-padded bucket list)

typedef __attribute__((ext_vector_type(8))) short short8v;   // 8 bf16
typedef __attribute__((ext_vector_type(4))) float f32x4;     // MFMA C/D frag

// fp32 -> bf16 round-to-nearest-even
__device__ __forceinline__ unsigned short f2bf(float f) {
  unsigned int u = __builtin_bit_cast(unsigned int, f);
  u += 0x7FFFu + ((u >> 16) & 1u);
  return (unsigned short)(u >> 16);
}

__device__ __forceinline__ float bf2f(unsigned short u) {
  return __builtin_bit_cast(float, (unsigned int)u << 16);
}

__device__ __forceinline__ short8v pack8(float4 a, float4 b) {
  short8v o;
  o[0] = (short)f2bf(a.x); o[1] = (short)f2bf(a.y);
  o[2] = (short)f2bf(a.z); o[3] = (short)f2bf(a.w);
  o[4] = (short)f2bf(b.x); o[5] = (short)f2bf(b.y);
  o[6] = (short)f2bf(b.z); o[7] = (short)f2bf(b.w);
  return o;
}

// ---------------------------------------------------------------------------
// Pack fp32 weight [batch][K][N] into MFMA B-fragment order:
// tile = b*(K/32)*(N/16) + kt*(N/16) + nt; elem j of lane l =
// W[b][kt*32 + 8*(l>>4) + j][nt*16 + (l&15)].
// ---------------------------------------------------------------------------
__global__ __launch_bounds__(256) void k_pack_w(
    const float* __restrict__ w, unsigned short* __restrict__ out,
    int Kdim, int Ndim, int batch) {
  const int tile = blockIdx.x * 4 + (threadIdx.x >> 6);
  const int l = threadIdx.x & 63;
  const int ntTiles = Ndim >> 4;
  const int tilesPer = (Kdim >> 5) * ntTiles;
  if (tile >= tilesPer * batch) return;
  const int bt = tile / tilesPer;
  const int rr = tile - bt * tilesPer;
  const int kt = rr / ntTiles, nt = rr % ntTiles;
  const float* wb = w + (size_t)bt * Kdim * Ndim;
  const int col = (nt << 4) + (l & 15);
  const int k0 = (kt << 5) + ((l >> 4) << 3);
  unsigned short* o = out + (((size_t)tile << 6) + l) * 8;
#pragma unroll
  for (int j = 0; j < 8; ++j) o[j] = f2bf(wb[(size_t)(k0 + j) * Ndim + col]);
}

// ---------------------------------------------------------------------------
// Node-type bucketing (padded segments, 32-aligned per type).
// ---------------------------------------------------------------------------
__global__ void k_count(const int* __restrict__ types, int* __restrict__ cnt) {
  const int n = blockIdx.x * 256 + threadIdx.x;
  if (n < N_NODES) atomicAdd(&cnt[types[n]], 1);
}
__global__ void k_prefix(const int* __restrict__ cnt, int* __restrict__ poff,
                         int* __restrict__ woff) {
  if (threadIdx.x == 0) {
    int cur = 0;
    for (int t = 0; t < TT; ++t) {
      poff[t] = cur; woff[t] = cur;
      cur += (cnt[t] + 31) & ~31;
    }
  }
}
__global__ void k_scatter(const int* __restrict__ types, int* __restrict__ woff,
                          int* __restrict__ bucket) {
  const int n = blockIdx.x * 256 + threadIdx.x;
  if (n < N_NODES) {
    const int pos = atomicAdd(&woff[types[n]], 1);
    bucket[pos] = n;
  }
}

// ---------------------------------------------------------------------------
// Type-batched node embedding: 32 nodes of ONE type per block.
// ---------------------------------------------------------------------------
__global__ __launch_bounds__(256) void k_node_embed_mfma(
    const float* __restrict__ x, const int* __restrict__ bucket,
    const int* __restrict__ types,
    const unsigned short* __restrict__ wp1, const float* __restrict__ b1,
    const unsigned short* __restrict__ wp2, const float* __restrict__ b2,
    unsigned short* __restrict__ nf0b) {
  __shared__ __align__(16) unsigned char A[32 * 512];   // 32 x 256 bf16
  __shared__ __align__(16) unsigned char Hb[32 * 256];  // 32 x 128 bf16
  __shared__ int sn[32];
  const int t = threadIdx.x;
  const int r0 = blockIdx.x * 32;
  if (t < 32) sn[t] = bucket[r0 + t];
  __syncthreads();
  if (sn[0] < 0) return;          // whole window is padding
  const int ty = types[sn[0]];

#pragma unroll
  for (int j = 0; j < 4; ++j) {
    const int q = j * 256 + t;
    const int i = q >> 5, c = q & 31;
    const int nd = sn[i];
    short8v o;
    if (nd >= 0) {
      const float* xr = x + (size_t)nd * DIN_NODE + c * 8;
      o = pack8(*reinterpret_cast<const float4*>(xr),
                *reinterpret_cast<const float4*>(xr + 4));
    } else {
#pragma unroll
      for (int k = 0; k < 8; ++k) o[k] = 0;
    }
    *reinterpret_cast<short8v*>(A + ((i * 512 + c * 16) ^ ((i & 7) << 4))) = o;
  }
  __syncthreads();

  const int w = t >> 6, l = t & 63, lr = l & 15, lg = l >> 4;
  const int sw = (lr & 7) << 4;
  const int row0 = lr, row1 = 16 + lr;

  f32x4 acc[2][2];
#pragma unroll
  for (int mt = 0; mt < 2; ++mt)
#pragma unroll
    for (int q = 0; q < 2; ++q)
#pragma unroll
      for (int r = 0; r < 4; ++r) acc[mt][q][r] = 0.f;

#pragma unroll
  for (int kt = 0; kt < 8; ++kt) {
    const short8v a0 = *reinterpret_cast<const short8v*>(
        A + ((row0 * 512 + kt * 64 + lg * 16) ^ sw));
    const short8v a1 = *reinterpret_cast<const short8v*>(
        A + ((row1 * 512 + kt * 64 + lg * 16) ^ sw));
#pragma unroll
    for (int q = 0; q < 2; ++q) {
      const short8v bq = *reinterpret_cast<const short8v*>(
          wp1 + (((size_t)(ty * 64 + kt * 8 + 2 * w + q) * 64 + l) << 3));
      acc[0][q] = __builtin_amdgcn_mfma_f32_16x16x32_bf16(a0, bq, acc[0][q], 0, 0, 0);
      acc[1][q] = __builtin_amdgcn_mfma_f32_16x16x32_bf16(a1, bq, acc[1][q], 0, 0, 0);
    }
  }
#pragma unroll
  for (int q = 0; q < 2; ++q) {
    const int col = (2 * w + q) * 16 + lr;
    const float bias = b1[ty * DF + col];
#pragma unroll
    for (int mt = 0; mt < 2; ++mt)
#pragma unroll
      for (int r = 0; r < 4; ++r) {
        const int row = mt * 16 + lg * 4 + r;
        *reinterpret_cast<unsigned short*>(
            Hb + ((row * 256 + col * 2) ^ ((row & 7) << 4))) =
            f2bf(fmaxf(acc[mt][q][r] + bias, 0.f));
      }
  }
  __syncthreads();

  f32x4 acc2[2][2];
#pragma unroll
  for (int mt = 0; mt < 2; ++mt)
#pragma unroll
    for (int q = 0; q < 2; ++q)
#pragma unroll
      for (int r = 0; r < 4; ++r) acc2[mt][q][r] = 0.f;
#pragma unroll
  for (int kt = 0; kt < 4; ++kt) {
    const short8v a0 = *reinterpret_cast<const short8v*>(
        Hb + ((row0 * 256 + kt * 64 + lg * 16) ^ sw));
    const short8v a1 = *reinterpret_cast<const short8v*>(
        Hb + ((row1 * 256 + kt * 64 + lg * 16) ^ sw));
#pragma unroll
    for (int q = 0; q < 2; ++q) {
      const short8v bq = *reinterpret_cast<const short8v*>(
          wp2 + (((size_t)(ty * 32 + kt * 8 + 2 * w + q) * 64 + l) << 3));
      acc2[0][q] = __builtin_amdgcn_mfma_f32_16x16x32_bf16(a0, bq, acc2[0][q], 0, 0, 0);
      acc2[1][q] = __builtin_amdgcn_mfma_f32_16x16x32_bf16(a1, bq, acc2[1][q], 0, 0, 0);
    }
  }
#pragma unroll
  for (int q = 0; q < 2; ++q) {
    const int col = (2 * w + q) * 16 + lr;
    const float bias = b2[ty * DF + col];
#pragma unroll
    for (int mt = 0; mt < 2; ++mt)
#pragma unroll
      for (int r = 0; r < 4; ++r) {
        const int row = mt * 16 + lg * 4 + r;
        const int nd = sn[row];
        if (nd >= 0)
          nf0b[(size_t)nd * DF + col] = f2bf(acc2[mt][q][r] + bias);
      }
  }
}

// ---------------------------------------------------------------------------
// Edge embedding MFMA: 64 -> 128 relu -> 128, 32 edges/block, bf16 out.
// ---------------------------------------------------------------------------
__global__ __launch_bounds__(256) void k_edge_embed_mfma(
    const float* __restrict__ ea,
    const unsigned short* __restrict__ wp1, const float* __restrict__ b1,
    const unsigned short* __restrict__ wp2, const float* __restrict__ b2,
    unsigned short* __restrict__ ef0b) {
  __shared__ __align__(16) unsigned char A[32 * 128];   // 32 x 64 bf16
  __shared__ __align__(16) unsigned char Hb[32 * 256];  // 32 x 128 bf16
  const int t = threadIdx.x;
  const int e0 = blockIdx.x * 32;
  {
    const int i = t >> 3, c = t & 7;
    const float* xr = ea + (size_t)(e0 + i) * DIN_EDGE + c * 8;
    const short8v o = pack8(*reinterpret_cast<const float4*>(xr),
                            *reinterpret_cast<const float4*>(xr + 4));
    *reinterpret_cast<short8v*>(A + ((i * 128 + c * 16) ^ ((i & 7) << 4))) = o;
  }
  __syncthreads();

  const int w = t >> 6, l = t & 63, lr = l & 15, lg = l >> 4;
  const int sw = (lr & 7) << 4;
  const int row0 = lr, row1 = 16 + lr;

  f32x4 acc[2][2];
#pragma unroll
  for (int mt = 0; mt < 2; ++mt)
#pragma unroll
    for (int q = 0; q < 2; ++q)
#pragma unroll
      for (int r = 0; r < 4; ++r) acc[mt][q][r] = 0.f;
#pragma unroll
  for (int kt = 0; kt < 2; ++kt) {
    const short8v a0 = *reinterpret_cast<const short8v*>(
        A + ((row0 * 128 + kt * 64 + lg * 16) ^ sw));
    const short8v a1 = *reinterpret_cast<const short8v*>(
        A + ((row1 * 128 + kt * 64 + lg * 16) ^ sw));
#pragma unroll
    for (int q = 0; q < 2; ++q) {
      const short8v bq = *reinterpret_cast<const short8v*>(
          wp1 + (((size_t)(kt * 8 + 2 * w + q) * 64 + l) << 3));
      acc[0][q] = __builtin_amdgcn_mfma_f32_16x16x32_bf16(a0, bq, acc[0][q], 0, 0, 0);
      acc[1][q] = __builtin_amdgcn_mfma_f32_16x16x32_bf16(a1, bq, acc[1][q], 0, 0, 0);
    }
  }
#pragma unroll
  for (int q = 0; q < 2; ++q) {
    const int col = (2 * w + q) * 16 + lr;
    const float bias = b1[col];
#pragma unroll
    for (int mt = 0; mt < 2; ++mt)
#pragma unroll
      for (int r = 0; r < 4; ++r) {
        const int row = mt * 16 + lg * 4 + r;
        *reinterpret_cast<unsigned short*>(
            Hb + ((row * 256 + col * 2) ^ ((row & 7) << 4))) =
            f2bf(fmaxf(acc[mt][q][r] + bias, 0.f));
      }
  }
  __syncthreads();

  f32x4 acc2[2][2];
#pragma unroll
  for (int mt = 0; mt < 2; ++mt)
#pragma unroll
    for (int q = 0; q < 2; ++q)
#pragma unroll
      for (int r = 0; r < 4; ++r) acc2[mt][q][r] = 0.f;
#pragma unroll
  for (int kt = 0; kt < 4; ++kt) {
    const short8v a0 = *reinterpret_cast<const short8v*>(
        Hb + ((row0 * 256 + kt * 64 + lg * 16) ^ sw));
    const short8v a1 = *reinterpret_cast<const short8v*>(
        Hb + ((row1 * 256 + kt * 64 + lg * 16) ^ sw));
#pragma unroll
    for (int q = 0; q < 2; ++q) {
      const short8v bq = *reinterpret_cast<const short8v*>(
          wp2 + (((size_t)(kt * 8 + 2 * w + q) * 64 + l) << 3));
      acc2[0][q] = __builtin_amdgcn_mfma_f32_16x16x32_bf16(a0, bq, acc2[0][q], 0, 0, 0);
      acc2[1][q] = __builtin_amdgcn_mfma_f32_16x16x32_bf16(a1, bq, acc2[1][q], 0, 0, 0);
    }
  }
#pragma unroll
  for (int q = 0; q < 2; ++q) {
    const int col = (2 * w + q) * 16 + lr;
    const float bias = b2[col];
#pragma unroll
    for (int mt = 0; mt < 2; ++mt)
#pragma unroll
      for (int r = 0; r < 4; ++r) {
        const int row = mt * 16 + lg * 4 + r;
        ef0b[(size_t)(e0 + row) * DF + col] = f2bf(acc2[mt][q][r] + bias);
      }
  }
}

// ---------------------------------------------------------------------------
// Per-node partial products for the edge MLP layer 1:
//   PD[n] = [nf0|nf] @ W1[0:256]   (dst part)
//   PS[n] = [nf0|nf] @ W1[256:512] (src part)
// 32 nodes/block, outputs bf16 [N][256].
// ---------------------------------------------------------------------------
__global__ __launch_bounds__(256) void k_partial(
    const unsigned short* __restrict__ nf0b, const unsigned short* __restrict__ nfb,
    const unsigned short* __restrict__ wpd, const unsigned short* __restrict__ wps,
    unsigned short* __restrict__ PDo, unsigned short* __restrict__ PSo) {
  __shared__ __align__(16) unsigned char A[32 * 512];   // 32 x 256 bf16
  const int t = threadIdx.x;
  const int n0 = blockIdx.x * 32;
#pragma unroll
  for (int j = 0; j < 4; ++j) {
    const int q = j * 256 + t;
    const int i = q >> 5, c = q & 31;
    const unsigned short* bp = (c < 16)
        ? nf0b + (size_t)(n0 + i) * DF + c * 8
        : nfb + (size_t)(n0 + i) * DF + (c - 16) * 8;
    *reinterpret_cast<short8v*>(A + ((i * 512 + c * 16) ^ ((i & 7) << 4))) =
        *reinterpret_cast<const short8v*>(bp);
  }
  __syncthreads();

  const int w = t >> 6, l = t & 63, lr = l & 15, lg = l >> 4;
  const int swz = (lr & 7) << 4;
  const int r0o = lr * 512 + lg * 16, r1o = (16 + lr) * 512 + lg * 16;

  f32x4 aD[2][4], aS[2][4];
#pragma unroll
  for (int mt = 0; mt < 2; ++mt)
#pragma unroll
    for (int q = 0; q < 4; ++q)
#pragma unroll
      for (int r = 0; r < 4; ++r) { aD[mt][q][r] = 0.f; aS[mt][q][r] = 0.f; }

#pragma unroll
  for (int kt = 0; kt < 8; ++kt) {
    const short8v a0 = *reinterpret_cast<const short8v*>(A + ((r0o + kt * 64) ^ swz));
    const short8v a1 = *reinterpret_cast<const short8v*>(A + ((r1o + kt * 64) ^ swz));
#pragma unroll
    for (int q = 0; q < 4; ++q) {
      const size_t bi = (((size_t)(kt * 16 + 4 * w + q) * 64 + l) << 3);
      const short8v bD = *reinterpret_cast<const short8v*>(wpd + bi);
      const short8v bS = *reinterpret_cast<const short8v*>(wps + bi);
      aD[0][q] = __builtin_amdgcn_mfma_f32_16x16x32_bf16(a0, bD, aD[0][q], 0, 0, 0);
      aD[1][q] = __builtin_amdgcn_mfma_f32_16x16x32_bf16(a1, bD, aD[1][q], 0, 0, 0);
      aS[0][q] = __builtin_amdgcn_mfma_f32_16x16x32_bf16(a0, bS, aS[0][q], 0, 0, 0);
      aS[1][q] = __builtin_amdgcn_mfma_f32_16x16x32_bf16(a1, bS, aS[1][q], 0, 0, 0);
    }
  }
#pragma unroll
  for (int q = 0; q < 4; ++q) {
    const int col = (4 * w + q) * 16 + lr;
#pragma unroll
    for (int mt = 0; mt < 2; ++mt)
#pragma unroll
      for (int r = 0; r < 4; ++r) {
        const int row = mt * 16 + lg * 4 + r;
        PDo[(size_t)(n0 + row) * HH + col] = f2bf(aD[mt][q][r]);
        PSo[(size_t)(n0 + row) * HH + col] = f2bf(aS[mt][q][r]);
      }
  }
}

// ---------------------------------------------------------------------------
// Edge MLP via MFMA v5 (split layer-1): 32 edges/block, 4 waves.
// hidden = relu(Pre + [ef0|ef]@W1_e + b1), Pre = PD[dst]+PS[src] (bf16 LDS).
// Layer-1 K=256 only; layer-2 unchanged.  LDS 32 KB -> 4 blocks/CU.
// ---------------------------------------------------------------------------
template <bool OUTF>
__global__ __launch_bounds__(256) void k_edge_mlp_mfma(
    const unsigned short* __restrict__ ef0, const unsigned short* __restrict__ ef_in,
    void* __restrict__ ef_out, float* __restrict__ agg,
    const int* __restrict__ srcv, const int* __restrict__ dstv,
    const unsigned short* __restrict__ wpe, const float* __restrict__ b1,
    const unsigned short* __restrict__ wp2, const float* __restrict__ b2,
    const unsigned short* __restrict__ PDi, const unsigned short* __restrict__ PSi) {
  __shared__ __align__(16) unsigned char A_lds[32 * 512];  // [ef0|ef] 16 KB
  __shared__ __align__(16) unsigned char P_lds[32 * 512];  // Pre / hidden 16 KB
  __shared__ int sd[2][32];
  const int t = threadIdx.x;
  const int e0 = blockIdx.x * 32;
  if (t < 32) sd[0][t] = srcv[e0 + t];
  else if (t < 64) sd[1][t - 32] = dstv[e0 + t - 32];

  // stage A = [ef0 | ef] (no sd dependency)
#pragma unroll
  for (int j = 0; j < 4; ++j) {
    const int q = j * 256 + t;
    const int i = q >> 5, c = q & 31;
    const unsigned short* bp = (c < 16)
        ? ef0 + (size_t)(e0 + i) * DF + c * 8
        : ef_in + (size_t)(e0 + i) * DF + (c - 16) * 8;
    *reinterpret_cast<short8v*>(A_lds + ((i * 512 + c * 16) ^ ((i & 7) << 4))) =
        *reinterpret_cast<const short8v*>(bp);
  }
  __syncthreads();   // sd visible

  // stage Pre = PD[dst] + PS[src]  -> bf16 LDS (same swizzled tile layout)
#pragma unroll
  for (int j = 0; j < 4; ++j) {
    const int q = j * 256 + t;
    const int i = q >> 5, c = q & 31;
    const short8v pd = *reinterpret_cast<const short8v*>(
        PDi + (size_t)sd[1][i] * HH + c * 8);
    const short8v ps = *reinterpret_cast<const short8v*>(
        PSi + (size_t)sd[0][i] * HH + c * 8);
    short8v o;
#pragma unroll
    for (int k = 0; k < 8; ++k)
      o[k] = (short)f2bf(bf2f((unsigned short)pd[k]) + bf2f((unsigned short)ps[k]));
    *reinterpret_cast<short8v*>(P_lds + ((i * 512 + c * 16) ^ ((i & 7) << 4))) = o;
  }
  __syncthreads();

  const int w = t >> 6, l = t & 63, lr = l & 15, lg = l >> 4;
  const int swz = (lr & 7) << 4;

  // ---- layer 1: acc init from Pre, then [32x256]@[256x256] ----------------
  f32x4 acc[2][4];
#pragma unroll
  for (int mt = 0; mt < 2; ++mt)
#pragma unroll
    for (int q = 0; q < 4; ++q) {
      const int col = (4 * w + q) * 16 + lr;
#pragma unroll
      for (int r = 0; r < 4; ++r) {
        const int row = mt * 16 + lg * 4 + r;
        const unsigned short u = *reinterpret_cast<const unsigned short*>(
            P_lds + ((row * 512 + col * 2) ^ ((row & 7) << 4)));
        acc[mt][q][r] = bf2f(u);
      }
    }

  const int r0o = lr * 512 + lg * 16;
  const int r1o = (16 + lr) * 512 + lg * 16;
  const unsigned short* wb1 = wpe + (((size_t)(4 * w) * 64 + l) << 3);
  // per-kt stride: 16 tiles * 512 = 8192 ushorts; per-q stride: 512

  short8v aR[3][2], bR[3][4];
#pragma unroll
  for (int s = 0; s < 2; ++s) {
    aR[s][0] = *reinterpret_cast<const short8v*>(A_lds + ((r0o + s * 64) ^ swz));
    aR[s][1] = *reinterpret_cast<const short8v*>(A_lds + ((r1o + s * 64) ^ swz));
#pragma unroll
    for (int q = 0; q < 4; ++q)
      bR[s][q] = *reinterpret_cast<const short8v*>(wb1 + (size_t)s * 8192 + q * 512);
  }
#pragma unroll
  for (int kt = 0; kt < 8; ++kt) {
    const int cur = kt % 3, pf = (kt + 2) % 3;
    if (kt < 6) {
      aR[pf][0] = *reinterpret_cast<const short8v*>(
          A_lds + ((r0o + (kt + 2) * 64) ^ swz));
      aR[pf][1] = *reinterpret_cast<const short8v*>(
          A_lds + ((r1o + (kt + 2) * 64) ^ swz));
#pragma unroll
      for (int q = 0; q < 4; ++q)
        bR[pf][q] = *reinterpret_cast<const short8v*>(
            wb1 + (size_t)(kt + 2) * 8192 + q * 512);
    }
#pragma unroll
    for (int q = 0; q < 4; ++q) {
      acc[0][q] = __builtin_amdgcn_mfma_f32_16x16x32_bf16(aR[cur][0], bR[cur][q],
                                                          acc[0][q], 0, 0, 0);
      acc[1][q] = __builtin_amdgcn_mfma_f32_16x16x32_bf16(aR[cur][1], bR[cur][q],
                                                          acc[1][q], 0, 0, 0);
    }
  }
  __syncthreads();   // done reading A_lds and P_lds

  // hidden (bias+relu) -> bf16 [32][256], overwrites P_lds
#pragma unroll
  for (int q = 0; q < 4; ++q) {
    const int col = (4 * w + q) * 16 + lr;
    const float bias = b1[col];
#pragma unroll
    for (int mt = 0; mt < 2; ++mt)
#pragma unroll
      for (int r = 0; r < 4; ++r) {
        const int row = mt * 16 + lg * 4 + r;
        *reinterpret_cast<unsigned short*>(
            P_lds + ((row * 512 + col * 2) ^ ((row & 7) << 4))) =
            f2bf(fmaxf(acc[mt][q][r] + bias, 0.f));
      }
  }
  __syncthreads();

  // ---- layer 2: [32x256] @ [256x128], wave w owns n-tiles 2w, 2w+1 ---------
  f32x4 acc2[2][2];
#pragma unroll
  for (int mt = 0; mt < 2; ++mt)
#pragma unroll
    for (int q = 0; q < 2; ++q)
#pragma unroll
      for (int r = 0; r < 4; ++r) acc2[mt][q][r] = 0.f;

  const int h0o = lr * 512 + lg * 16;
  const int h1o = (16 + lr) * 512 + lg * 16;
  const unsigned short* wb2 = wp2 + (((size_t)(2 * w) * 64 + l) << 3);
  // per-kt stride: 8 tiles * 512 = 4096 ushorts

  short8v aS[3][2], bS[3][2];
#pragma unroll
  for (int s = 0; s < 2; ++s) {
    aS[s][0] = *reinterpret_cast<const short8v*>(P_lds + ((h0o + s * 64) ^ swz));
    aS[s][1] = *reinterpret_cast<const short8v*>(P_lds + ((h1o + s * 64) ^ swz));
#pragma unroll
    for (int q = 0; q < 2; ++q)
      bS[s][q] = *reinterpret_cast<const short8v*>(wb2 + (size_t)s * 4096 + q * 512);
  }
#pragma unroll
  for (int kt = 0; kt < 8; ++kt) {
    const int cur = kt % 3, pf = (kt + 2) % 3;
    if (kt < 6) {
      aS[pf][0] = *reinterpret_cast<const short8v*>(
          P_lds + ((h0o + (kt + 2) * 64) ^ swz));
      aS[pf][1] = *reinterpret_cast<const short8v*>(
          P_lds + ((h1o + (kt + 2) * 64) ^ swz));
#pragma unroll
      for (int q = 0; q < 2; ++q)
        bS[pf][q] = *reinterpret_cast<const short8v*>(
            wb2 + (size_t)(kt + 2) * 4096 + q * 512);
    }
#pragma unroll
    for (int q = 0; q < 2; ++q) {
      acc2[0][q] = __builtin_amdgcn_mfma_f32_16x16x32_bf16(aS[cur][0], bS[cur][q],
                                                           acc2[0][q], 0, 0, 0);
      acc2[1][q] = __builtin_amdgcn_mfma_f32_16x16x32_bf16(aS[cur][1], bS[cur][q],
                                                           acc2[1][q], 0, 0, 0);
    }
  }

  // ---- epilogue: bias, store ef, atomic agg[dst] ---------------------------
#pragma unroll
  for (int q = 0; q < 2; ++q) {
    const int n = (2 * w + q) * 16 + lr;
    const float bias = b2[n];
#pragma unroll
    for (int mt = 0; mt < 2; ++mt)
#pragma unroll
      for (int r = 0; r < 4; ++r) {
        const int m = mt * 16 + lg * 4 + r;
        const float v = acc2[mt][q][r] + bias;
        if (OUTF)
          ((float*)ef_out)[(size_t)(e0 + m) * DF + n] = v;
        else
          ((unsigned short*)ef_out)[(size_t)(e0 + m) * DF + n] = f2bf(v);
        atomicAdd(&agg[(size_t)sd[1][m] * DF + n], v);
      }
  }
}

// ---------------------------------------------------------------------------
// Node update MFMA: [nf0|nf|agg] (384) @ w + b, 32 nodes/block.
// ---------------------------------------------------------------------------
template <bool OUTF>
__global__ __launch_bounds__(256) void k_node_update_mfma(
    const unsigned short* __restrict__ nf0, const unsigned short* __restrict__ nfb,
    const float* __restrict__ agg, void* __restrict__ outp,
    const unsigned short* __restrict__ wp, const float* __restrict__ b) {
  __shared__ __align__(16) unsigned char A[32 * 768];   // 32 x 384 bf16
  const int t = threadIdx.x;
  const int n0 = blockIdx.x * 32;
#pragma unroll
  for (int j = 0; j < 6; ++j) {
    const int q = j * 256 + t;
    const int i = q / 48;
    const int cc = q - i * 48;
    const int p = cc >> 4, c = cc & 15;
    const int row = n0 + i;
    short8v o;
    if (p == 0)
      o = *reinterpret_cast<const short8v*>(nf0 + (size_t)row * DF + c * 8);
    else if (p == 1)
      o = *reinterpret_cast<const short8v*>(nfb + (size_t)row * DF + c * 8);
    else {
      const float* ar = agg + (size_t)row * DF + c * 8;
      o = pack8(*reinterpret_cast<const float4*>(ar),
                *reinterpret_cast<const float4*>(ar + 4));
    }
    *reinterpret_cast<short8v*>(
        A + ((i * 768 + p * 256 + c * 16) ^ ((i & 7) << 4))) = o;
  }
  __syncthreads();

  const int w = t >> 6, l = t & 63, lr = l & 15, lg = l >> 4;
  const int sw = (lr & 7) << 4;
  const int row0 = lr, row1 = 16 + lr;

  f32x4 acc[2][2];
#pragma unroll
  for (int mt = 0; mt < 2; ++mt)
#pragma unroll
    for (int q = 0; q < 2; ++q)
#pragma unroll
      for (int r = 0; r < 4; ++r) acc[mt][q][r] = 0.f;
#pragma unroll
  for (int kt = 0; kt < 12; ++kt) {
    const short8v a0 = *reinterpret_cast<const short8v*>(
        A + ((row0 * 768 + kt * 64 + lg * 16) ^ sw));
    const short8v a1 = *reinterpret_cast<const short8v*>(
        A + ((row1 * 768 + kt * 64 + lg * 16) ^ sw));
#pragma unroll
    for (int q = 0; q < 2; ++q) {
      const short8v bq = *reinterpret_cast<const short8v*>(
          wp + (((size_t)(kt * 8 + 2 * w + q) * 64 + l) << 3));
      acc[0][q] = __builtin_amdgcn_mfma_f32_16x16x32_bf16(a0, bq, acc[0][q], 0, 0, 0);
      acc[1][q] = __builtin_amdgcn_mfma_f32_16x16x32_bf16(a1, bq, acc[1][q], 0, 0, 0);
    }
  }
#pragma unroll
  for (int q = 0; q < 2; ++q) {
    const int col = (2 * w + q) * 16 + lr;
    const float bias = b[col];
#pragma unroll
    for (int mt = 0; mt < 2; ++mt)
#pragma unroll
      for (int r = 0; r < 4; ++r) {
        const int row = mt * 16 + lg * 4 + r;
        const float v = acc[mt][q][r] + bias;
        if (OUTF)
          ((float*)outp)[(size_t)(n0 + row) * DF + col] = v;
        else
          ((unsigned short*)outp)[(size_t)(n0 + row) * DF + col] = f2bf(v);
      }
  }
}

// ---------------------------------------------------------------------------
// Scalar classifier: relu(f @ w1 + b1) . w2 + b2, 32 rows/block.
// ---------------------------------------------------------------------------
template <bool INBF>
__global__ __launch_bounds__(256) void k_cls_scalar_mfma(
    const void* __restrict__ feat, const unsigned short* __restrict__ wp,
    const float* __restrict__ b1, const float* __restrict__ w2,
    const float* __restrict__ b2, float* __restrict__ out) {
  __shared__ __align__(16) unsigned char A[32 * 256];  // 32 x 128 bf16
  __shared__ float hid[32][136];
  __shared__ float w2s[DF];
  __shared__ float part[32][8];
  const int t = threadIdx.x;
  const int r0 = blockIdx.x * 32;
  if (t < DF) w2s[t] = w2[t];
#pragma unroll
  for (int j = 0; j < 2; ++j) {
    const int q = j * 256 + t;
    const int i = q >> 4, c = q & 15;
    short8v o;
    if (INBF) {
      o = *reinterpret_cast<const short8v*>(
          (const unsigned short*)feat + (size_t)(r0 + i) * DF + c * 8);
    } else {
      const float* fr = (const float*)feat + (size_t)(r0 + i) * DF + c * 8;
      o = pack8(*reinterpret_cast<const float4*>(fr),
                *reinterpret_cast<const float4*>(fr + 4));
    }
    *reinterpret_cast<short8v*>(A + ((i * 256 + c * 16) ^ ((i & 7) << 4))) = o;
  }
  __syncthreads();

  const int w = t >> 6, l = t & 63, lr = l & 15, lg = l >> 4;
  const int sw = (lr & 7) << 4;
  const int row0 = lr, row1 = 16 + lr;
  f32x4 acc[2][2];
#pragma unroll
  for (int mt = 0; mt < 2; ++mt)
#pragma unroll
    for (int q = 0; q < 2; ++q)
#pragma unroll
      for (int r = 0; r < 4; ++r) acc[mt][q][r] = 0.f;
#pragma unroll
  for (int kt = 0; kt < 4; ++kt) {
    const short8v a0 = *reinterpret_cast<const short8v*>(
        A + ((row0 * 256 + kt * 64 + lg * 16) ^ sw));
    const short8v a1 = *reinterpret_cast<const short8v*>(
        A + ((row1 * 256 + kt * 64 + lg * 16) ^ sw));
#pragma unroll
    for (int q = 0; q < 2; ++q) {
      const short8v bq = *reinterpret_cast<const short8v*>(
          wp + (((size_t)(kt * 8 + 2 * w + q) * 64 + l) << 3));
      acc[0][q] = __builtin_amdgcn_mfma_f32_16x16x32_bf16(a0, bq, acc[0][q], 0, 0, 0);
      acc[1][q] = __builtin_amdgcn_mfma_f32_16x16x32_bf16(a1, bq, acc[1][q], 0, 0, 0);
    }
  }
#pragma unroll
  for (int q = 0; q < 2; ++q) {
    const int col = (2 * w + q) * 16 + lr;
    const float bias = b1[col];
#pragma unroll
    for (int mt = 0; mt < 2; ++mt)
#pragma unroll
      for (int r = 0; r < 4; ++r) {
        const int row = mt * 16 + lg * 4 + r;
        hid[row][col] = fmaxf(acc[mt][q][r] + bias, 0.f);
      }
  }
  __syncthreads();
  {
    const int r = t >> 3, kc = t & 7;
    float s = 0.f;
#pragma unroll
    for (int u = 0; u < 16; ++u) s = fmaf(hid[r][kc * 16 + u], w2s[kc * 16 + u], s);
    part[r][kc] = s;
  }
  __syncthreads();
  if (t < 32) {
    float s = b2[0];
#pragma unroll
    for (int k = 0; k < 8; ++k) s += part[t][k];
    out[r0 + t] = s;
  }
}

// ---------------------------------------------------------------------------
// Class classifier: relu(f @ w1 + b1) @ w2[128,17] + b2, fp32 input.
// ---------------------------------------------------------------------------
__global__ __launch_bounds__(256) void k_cls_class_mfma(
    const float* __restrict__ feat, const unsigned short* __restrict__ wp,
    const float* __restrict__ b1, const float* __restrict__ w2,
    const float* __restrict__ b2, float* __restrict__ out) {
  __shared__ __align__(16) unsigned char A[32 * 256];
  __shared__ float hid[32][136];
  __shared__ float w2s[DF * TT];
  const int t = threadIdx.x;
  const int r0 = blockIdx.x * 32;
  for (int j = t; j < DF * TT; j += 256) w2s[j] = w2[j];
#pragma unroll
  for (int j = 0; j < 2; ++j) {
    const int q = j * 256 + t;
    const int i = q >> 4, c = q & 15;
    const float* fr = feat + (size_t)(r0 + i) * DF + c * 8;
    const short8v o = pack8(*reinterpret_cast<const float4*>(fr),
                            *reinterpret_cast<const float4*>(fr + 4));
    *reinterpret_cast<short8v*>(A + ((i * 256 + c * 16) ^ ((i & 7) << 4))) = o;
  }
  __syncthreads();

  const int w = t >> 6, l = t & 63, lr = l & 15, lg = l >> 4;
  const int sw = (lr & 7) << 4;
  const int row0 = lr, row1 = 16 + lr;
  f32x4 acc[2][2];
#pragma unroll
  for (int mt = 0; mt < 2; ++mt)
#pragma unroll
    for (int q = 0; q < 2; ++q)
#pragma unroll
      for (int r = 0; r < 4; ++r) acc[mt][q][r] = 0.f;
#pragma unroll
  for (int kt = 0; kt < 4; ++kt) {
    const short8v a0 = *reinterpret_cast<const short8v*>(
        A + ((row0 * 256 + kt * 64 + lg * 16) ^ sw));
    const short8v a1 = *reinterpret_cast<const short8v*>(
        A + ((row1 * 256 + kt * 64 + lg * 16) ^ sw));
#pragma unroll
    for (int q = 0; q < 2; ++q) {
      const short8v bq = *reinterpret_cast<const short8v*>(
          wp + (((size_t)(kt * 8 + 2 * w + q) * 64 + l) << 3));
      acc[0][q] = __builtin_amdgcn_mfma_f32_16x16x32_bf16(a0, bq, acc[0][q], 0, 0, 0);
      acc[1][q] = __builtin_amdgcn_mfma_f32_16x16x32_bf16(a1, bq, acc[1][q], 0, 0, 0);
    }
  }
#pragma unroll
  for (int q = 0; q < 2; ++q) {
    const int col = (2 * w + q) * 16 + lr;
    const float bias = b1[col];
#pragma unroll
    for (int mt = 0; mt < 2; ++mt)
#pragma unroll
      for (int r = 0; r < 4; ++r) {
        const int row = mt * 16 + lg * 4 + r;
        hid[row][col] = fmaxf(acc[mt][q][r] + bias, 0.f);
      }
  }
  __syncthreads();
  for (int o = t; o < 32 * TT; o += 256) {
    const int r = o / TT, c = o - TT * r;
    float s = b2[c];
    for (int k = 0; k < DF; ++k) s = fmaf(hid[r][k], w2s[k * TT + c], s);
    out[(size_t)(r0 + r) * TT + c] = s;
  }
}

// ---------------------------------------------------------------------------
extern "C" void kernel_launch(void* const* d_in, const int* in_sizes, int n_in,
                              void* d_out, int out_size, void* d_ws,
                              size_t ws_size, hipStream_t stream) {
  (void)in_sizes; (void)n_in; (void)out_size; (void)ws_size;
  const float* x         = (const float*)d_in[0];
  const float* edge_attr = (const float*)d_in[1];
  const int*   edge_idx  = (const int*)d_in[2];
  const int*   node_ty   = (const int*)d_in[3];
  const float* ne_w1 = (const float*)d_in[4];
  const float* ne_b1 = (const float*)d_in[5];
  const float* ne_w2 = (const float*)d_in[6];
  const float* ne_b2 = (const float*)d_in[7];
  const float* ee_w1 = (const float*)d_in[8];
  const float* ee_b1 = (const float*)d_in[9];
  const float* ee_w2 = (const float*)d_in[10];
  const float* ee_b2 = (const float*)d_in[11];
  const float* me_w1 = (const float*)d_in[12];
  const float* me_b1 = (const float*)d_in[13];
  const float* me_w2 = (const float*)d_in[14];
  const float* me_b2 = (const float*)d_in[15];
  const float* mn_w1 = (const float*)d_in[16];
  const float* mn_b1 = (const float*)d_in[17];
  const float* ec_w1 = (const float*)d_in[18];
  const float* ec_b1 = (const float*)d_in[19];
  const float* ec_w2 = (const float*)d_in[20];
  const float* ec_b2 = (const float*)d_in[21];
  const float* nc_w1 = (const float*)d_in[22];
  const float* nc_b1 = (const float*)d_in[23];
  const float* nc_w2 = (const float*)d_in[24];
  const float* nc_b2 = (const float*)d_in[25];
  const float* cc_w1 = (const float*)d_in[26];
  const float* cc_b1 = (const float*)d_in[27];
  const float* cc_w2 = (const float*)d_in[28];
  const float* cc_b2 = (const float*)d_in[29];

  const int* srcv = edge_idx;
  const int* dstv = edge_idx + N_EDGES;

  // ---- workspace layout ----
  float* agg = (float*)d_ws;                               // 2.56M f
  unsigned short* nf0b = (unsigned short*)(agg + (size_t)N_NODES * DF);
  unsigned short* nf1b = nf0b + (size_t)N_NODES * DF;
  unsigned short* ef0b = nf1b + (size_t)N_NODES * DF;
  unsigned short* ef1b = ef0b + (size_t)N_EDGES * DF;
  unsigned short* wmpD = ef1b + (size_t)N_EDGES * DF;      // W1 rows 0:256   (256x256)
  unsigned short* wmpS = wmpD + 256 * 256;                 // W1 rows 256:512 (256x256)
  unsigned short* wmeE = wmpS + 256 * 256;                 // W1 rows 512:768 (256x256)
  unsigned short* wme2 = wmeE + 256 * 256;                 // 256x128
  unsigned short* wmn  = wme2 + 256 * 128;                 // 384x128
  unsigned short* wne1 = wmn + 384 * 128;                  // 17 x 256x128
  unsigned short* wne2 = wne1 + (size_t)TT * 256 * 128;    // 17 x 128x128
  unsigned short* wee1 = wne2 + (size_t)TT * 128 * 128;    // 64x128
  unsigned short* wee2 = wee1 + 64 * 128;                  // 128x128
  unsigned short* wec  = wee2 + 128 * 128;
  unsigned short* wnc  = wec + 128 * 128;
  unsigned short* wcc  = wnc + 128 * 128;
  unsigned short* PD   = wcc + 128 * 128;                  // [N][256] bf16
  unsigned short* PS   = PD + (size_t)N_NODES * HH;        // [N][256] bf16
  int* cnt    = (int*)(PS + (size_t)N_NODES * HH);
  int* poff   = cnt + 32;
  int* woff   = poff + 32;
  int* bucket = woff + 32;                                 // 20544 ints

  // ---- output layout ----
  float* out_pe = (float*)d_out;
  float* out_pn = out_pe + N_EDGES;
  float* out_pc = out_pn + N_NODES;
  float* out_nf = out_pc + (size_t)N_NODES * TT;
  float* out_ef = out_nf + (size_t)N_NODES * DF;

  // ---- weight packing ----
  k_pack_w<<<32, 256, 0, stream>>>(me_w1, wmpD, 256, 256, 1);
  k_pack_w<<<32, 256, 0, stream>>>(me_w1 + 256 * 256, wmpS, 256, 256, 1);
  k_pack_w<<<32, 256, 0, stream>>>(me_w1 + 512 * 256, wmeE, 256, 256, 1);
  k_pack_w<<<16, 256, 0, stream>>>(me_w2, wme2, 256, 128, 1);
  k_pack_w<<<24, 256, 0, stream>>>(mn_w1, wmn, 384, 128, 1);
  k_pack_w<<<272, 256, 0, stream>>>(ne_w1, wne1, 256, 128, TT);
  k_pack_w<<<136, 256, 0, stream>>>(ne_w2, wne2, 128, 128, TT);
  k_pack_w<<<4, 256, 0, stream>>>(ee_w1, wee1, 64, 128, 1);
  k_pack_w<<<8, 256, 0, stream>>>(ee_w2, wee2, 128, 128, 1);
  k_pack_w<<<8, 256, 0, stream>>>(ec_w1, wec, 128, 128, 1);
  k_pack_w<<<8, 256, 0, stream>>>(nc_w1, wnc, 128, 128, 1);
  k_pack_w<<<8, 256, 0, stream>>>(cc_w1, wcc, 128, 128, 1);

  // ---- type bucketing ----
  hipMemsetAsync(cnt, 0, 32 * sizeof(int), stream);
  hipMemsetAsync(bucket, 0xFF, NE_PAD_SLOTS * sizeof(int), stream);
  k_count<<<(N_NODES + 255) / 256, 256, 0, stream>>>(node_ty, cnt);
  k_prefix<<<1, 64, 0, stream>>>(cnt, poff, woff);
  k_scatter<<<(N_NODES + 255) / 256, 256, 0, stream>>>(node_ty, woff, bucket);

  // ---- embeddings ----
  k_node_embed_mfma<<<NE_PAD_SLOTS / 32, 256, 0, stream>>>(
      x, bucket, node_ty, wne1, ne_b1, wne2, ne_b2, nf0b);
  k_edge_embed_mfma<<<N_EDGES / 32, 256, 0, stream>>>(edge_attr, wee1, ee_b1,
                                                      wee2, ee_b2, ef0b);

  // ---- mp step 1 (nf = nf0, ef = ef0) ----
  hipMemsetAsync(agg, 0, (size_t)N_NODES * DF * sizeof(float), stream);
  k_partial<<<N_NODES / 32, 256, 0, stream>>>(nf0b, nf0b, wmpD, wmpS, PD, PS);
  k_edge_mlp_mfma<false><<<N_EDGES / 32, 256, 0, stream>>>(
      ef0b, ef0b, (void*)ef1b, agg, srcv, dstv, wmeE, me_b1, wme2, me_b2, PD, PS);
  k_node_update_mfma<false><<<N_NODES / 32, 256, 0, stream>>>(
      nf0b, nf0b, agg, (void*)nf1b, wmn, mn_b1);
  // ---- mp step 2 ----
  hipMemsetAsync(agg, 0, (size_t)N_NODES * DF * sizeof(float), stream);
  k_partial<<<N_NODES / 32, 256, 0, stream>>>(nf0b, nf1b, wmpD, wmpS, PD, PS);
  k_edge_mlp_mfma<false><<<N_EDGES / 32, 256, 0, stream>>>(
      ef0b, ef1b, (void*)ef1b, agg, srcv, dstv, wmeE, me_b1, wme2, me_b2, PD, PS);
  k_node_update_mfma<false><<<N_NODES / 32, 256, 0, stream>>>(
      nf0b, nf1b, agg, (void*)nf1b, wmn, mn_b1);
  // pred_edge from ef after 2 steps
  k_cls_scalar_mfma<true><<<N_EDGES / 32, 256, 0, stream>>>(
      (const void*)ef1b, wec, ec_b1, ec_w2, ec_b2, out_pe);
  // ---- mp step 3 ----
  hipMemsetAsync(agg, 0, (size_t)N_NODES * DF * sizeof(float), stream);
  k_partial<<<N_NODES / 32, 256, 0, stream>>>(nf0b, nf1b, wmpD, wmpS, PD, PS);
  k_edge_mlp_mfma<true><<<N_EDGES / 32, 256, 0, stream>>>(
      ef0b, ef1b, (void*)out_ef, agg, srcv, dstv, wmeE, me_b1, wme2, me_b2, PD, PS);
  k_node_update_mfma<true><<<N_NODES / 32, 256, 0, stream>>>(
      nf0b, nf1b, agg, (void*)out_nf, wmn, mn_b1);

  // ---- heads ----
  k_cls_scalar_mfma<false><<<N_NODES / 32, 256, 0, stream>>>(
      (const void*)out_nf, wnc, nc_b1, nc_w2, nc_b2, out_pn);
  k_cls_class_mfma<<<N_NODES / 32, 256, 0, stream>>>(out_nf, wcc, cc_b1, cc_w2,
                                                     cc_b2, out_pc);
}